// Round 1
// baseline (1443.495 us; speedup 1.0000x reference)
//
#include <hip/hip_runtime.h>

typedef __bf16 bf16x8 __attribute__((ext_vector_type(8)));
typedef float f32x4 __attribute__((ext_vector_type(4)));
typedef float f4 __attribute__((ext_vector_type(4)));
typedef unsigned short us8 __attribute__((ext_vector_type(8)));

#define T_TOK 8192
#define DDIM 1024
#define NEXP 8
#define IDIM 2048

__device__ __forceinline__ unsigned short f2bf(float f) {
    unsigned u = __float_as_uint(f);
    u += 0x7fffu + ((u >> 16) & 1u);   // round-to-nearest-even
    return (unsigned short)(u >> 16);
}

// ---------------- Router: gate logits (fp32), softmax/top2 weights, shared sigmoid gate ----------------
__global__ __launch_bounds__(256) void router_kernel(
    const float* __restrict__ x, const float* __restrict__ gate_w,
    const float* __restrict__ sgw, float* __restrict__ gate_out,
    float* __restrict__ wdense, float* __restrict__ sgout)
{
    __shared__ float lgw[DDIM * NEXP];
    __shared__ float lsg[DDIM];
    int tid = threadIdx.x;
    for (int i = tid; i < (DDIM * NEXP) / 4; i += 256)
        ((f4*)lgw)[i] = ((const f4*)gate_w)[i];
    for (int i = tid; i < DDIM / 4; i += 256)
        ((f4*)lsg)[i] = ((const f4*)sgw)[i];
    __syncthreads();

    int wid = tid >> 6, l = tid & 63;
    int t = blockIdx.x * 4 + wid;

    float acc[NEXP];
#pragma unroll
    for (int e = 0; e < NEXP; e++) acc[e] = 0.f;
    float accs = 0.f;
    const float* xr = x + (size_t)t * DDIM;
#pragma unroll
    for (int j = 0; j < 4; j++) {
        int d0 = j * 256 + l * 4;
        f4 xv = *(const f4*)(xr + d0);
#pragma unroll
        for (int c = 0; c < 4; c++) {
            float xd = xv[c];
            int d = d0 + c;
#pragma unroll
            for (int e = 0; e < NEXP; e++) acc[e] += xd * lgw[d * NEXP + e];
            accs += xd * lsg[d];
        }
    }
#pragma unroll
    for (int off = 32; off > 0; off >>= 1) {
#pragma unroll
        for (int e = 0; e < NEXP; e++) acc[e] += __shfl_xor(acc[e], off);
        accs += __shfl_xor(accs, off);
    }
    if (l == 0) {
        float m = acc[0];
        for (int e = 1; e < NEXP; e++) m = fmaxf(m, acc[e]);
        float p[NEXP], s = 0.f;
        for (int e = 0; e < NEXP; e++) { p[e] = __expf(acc[e] - m); s += p[e]; }
        float inv = 1.f / s;
        int i1 = 0; float b1 = p[0];
        for (int e = 1; e < NEXP; e++) if (p[e] > b1) { b1 = p[e]; i1 = e; }
        int i2 = -1; float b2 = -1.f;
        for (int e = 0; e < NEXP; e++) if (e != i1 && p[e] > b2) { b2 = p[e]; i2 = e; }
        for (int e = 0; e < NEXP; e++) {
            gate_out[(size_t)t * NEXP + e] = acc[e];
            float w = (e == i1) ? b1 * inv : (e == i2) ? b2 * inv : 0.f;
            wdense[(size_t)t * NEXP + e] = w;
        }
        sgout[t] = 1.f / (1.f + __expf(-accs));
    }
}

// ---------------- fp32 -> bf16 (same layout), 8 elems/thread ----------------
__global__ __launch_bounds__(256) void cvt_kernel(
    const float* __restrict__ in, unsigned short* __restrict__ out, int n8)
{
    int i = blockIdx.x * 256 + threadIdx.x;
    if (i >= n8) return;
    const f4* p = (const f4*)in + (size_t)i * 2;
    f4 a = p[0], b = p[1];
    us8 o;
#pragma unroll
    for (int k = 0; k < 4; k++) { o[k] = f2bf(a[k]); o[4 + k] = f2bf(b[k]); }
    *((us8*)out + i) = o;
}

// ---------------- fp32 [R,C] -> bf16 [C,R] transpose-convert, 64x64 LDS tiles ----------------
__global__ __launch_bounds__(256) void transcvt_kernel(
    const float* __restrict__ in, unsigned short* __restrict__ out, int R, int C)
{
    __shared__ unsigned short lds[64][72];
    int t = threadIdx.x;
    int c0 = blockIdx.x * 64, r0 = blockIdx.y * 64;
    int tr = t >> 4, tc = (t & 15) * 4;
#pragma unroll
    for (int j = 0; j < 4; j++) {
        int r = tr + j * 16;
        f4 v = *(const f4*)(in + (size_t)(r0 + r) * C + c0 + tc);
#pragma unroll
        for (int k = 0; k < 4; k++) lds[r][tc + k] = f2bf(v[k]);
    }
    __syncthreads();
    int orow = t >> 2, s = t & 3;
    us8 v0, v1;
#pragma unroll
    for (int i = 0; i < 8; i++) {
        v0[i] = lds[s * 16 + i][orow];
        v1[i] = lds[s * 16 + 8 + i][orow];
    }
    unsigned short* op = out + (size_t)(c0 + orow) * R + r0 + s * 16;
    *(us8*)op = v0;
    *(us8*)(op + 8) = v1;
}

// ---------------- GEMM helpers: 128x128 tile, BK=32, global_load_lds staging ----------------
__device__ __forceinline__ void stage_tile(
    const unsigned short* __restrict__ g, int row0, int ldk, int k0,
    unsigned short* lds, int wid, int lane)
{
#pragma unroll
    for (int j = 0; j < 2; j++) {
        int c = wid + j * 4;              // chunk 0..7, 1KB each
        int seg = c * 64 + lane;          // seg = row*4 + kseg
        int row = seg >> 2, ks = seg & 3;
        const unsigned short* gp = g + (size_t)(row0 + row) * ldk + k0 + ks * 8;
        __builtin_amdgcn_global_load_lds(
            (const __attribute__((address_space(1))) void*)gp,
            (__attribute__((address_space(3))) void*)(lds + c * 512),
            16, 0, 0);
    }
}

// Fused gate+up GEMM with SwiGLU epilogue: H = silu(A@Bg^T) * (A@Bu^T), bf16 out.
// A: [M,K] bf16 row-major; Bg,Bu: [N,K] bf16 row-major (pre-transposed weights).
__global__ __launch_bounds__(256, 2) void gemm_gateup(
    const unsigned short* __restrict__ A, const unsigned short* __restrict__ Bg,
    const unsigned short* __restrict__ Bu, unsigned short* __restrict__ H,
    int M, int N, int K)
{
    __shared__ unsigned short As[128 * 32], Bgs[128 * 32], Bus[128 * 32];
    int tid = threadIdx.x, wid = tid >> 6, l = tid & 63;
    int wm = wid >> 1, wn = wid & 1;
    int lr = l & 15, kg = l >> 4;
    int m0 = blockIdx.y * 128, n0 = blockIdx.x * 128;

    f32x4 zero = {0.f, 0.f, 0.f, 0.f};
    f32x4 accg[4][4], accu[4][4];
#pragma unroll
    for (int m = 0; m < 4; m++)
#pragma unroll
        for (int n = 0; n < 4; n++) { accg[m][n] = zero; accu[m][n] = zero; }

    for (int k0 = 0; k0 < K; k0 += 32) {
        stage_tile(A, m0, K, k0, As, wid, l);
        stage_tile(Bg, n0, K, k0, Bgs, wid, l);
        stage_tile(Bu, n0, K, k0, Bus, wid, l);
        __syncthreads();
        bf16x8 a[4], bg[4], bu[4];
#pragma unroll
        for (int m = 0; m < 4; m++)
            a[m] = *(const bf16x8*)(As + ((wm * 64 + m * 16 + lr) * 32 + kg * 8));
#pragma unroll
        for (int n = 0; n < 4; n++) {
            bg[n] = *(const bf16x8*)(Bgs + ((wn * 64 + n * 16 + lr) * 32 + kg * 8));
            bu[n] = *(const bf16x8*)(Bus + ((wn * 64 + n * 16 + lr) * 32 + kg * 8));
        }
#pragma unroll
        for (int m = 0; m < 4; m++)
#pragma unroll
            for (int n = 0; n < 4; n++) {
                accg[m][n] = __builtin_amdgcn_mfma_f32_16x16x32_bf16(a[m], bg[n], accg[m][n], 0, 0, 0);
                accu[m][n] = __builtin_amdgcn_mfma_f32_16x16x32_bf16(a[m], bu[n], accu[m][n], 0, 0, 0);
            }
        __syncthreads();
    }

#pragma unroll
    for (int m = 0; m < 4; m++) {
        int row = m0 + wm * 64 + m * 16 + kg * 4;
#pragma unroll
        for (int n = 0; n < 4; n++) {
            int col = n0 + wn * 64 + n * 16 + lr;
#pragma unroll
            for (int r = 0; r < 4; r++) {
                float g = accg[m][n][r], u = accu[m][n][r];
                float hv = g * (1.f / (1.f + __expf(-g))) * u;
                H[(size_t)(row + r) * N + col] = f2bf(hv);
            }
        }
    }
}

// Down GEMM with per-row combine weight: Out[t,:] (+)= coef[t] * (A@B^T)[t,:]
__global__ __launch_bounds__(256, 2) void gemm_down(
    const unsigned short* __restrict__ A, const unsigned short* __restrict__ B,
    float* __restrict__ Out, const float* __restrict__ coef, int cstride,
    int accum, int M, int N, int K)
{
    __shared__ unsigned short As[128 * 32], Bs[128 * 32];
    int tid = threadIdx.x, wid = tid >> 6, l = tid & 63;
    int wm = wid >> 1, wn = wid & 1;
    int lr = l & 15, kg = l >> 4;
    int m0 = blockIdx.y * 128, n0 = blockIdx.x * 128;

    f32x4 zero = {0.f, 0.f, 0.f, 0.f};
    f32x4 acc[4][4];
#pragma unroll
    for (int m = 0; m < 4; m++)
#pragma unroll
        for (int n = 0; n < 4; n++) acc[m][n] = zero;

    for (int k0 = 0; k0 < K; k0 += 32) {
        stage_tile(A, m0, K, k0, As, wid, l);
        stage_tile(B, n0, K, k0, Bs, wid, l);
        __syncthreads();
        bf16x8 a[4], b[4];
#pragma unroll
        for (int m = 0; m < 4; m++)
            a[m] = *(const bf16x8*)(As + ((wm * 64 + m * 16 + lr) * 32 + kg * 8));
#pragma unroll
        for (int n = 0; n < 4; n++)
            b[n] = *(const bf16x8*)(Bs + ((wn * 64 + n * 16 + lr) * 32 + kg * 8));
#pragma unroll
        for (int m = 0; m < 4; m++)
#pragma unroll
            for (int n = 0; n < 4; n++)
                acc[m][n] = __builtin_amdgcn_mfma_f32_16x16x32_bf16(a[m], b[n], acc[m][n], 0, 0, 0);
        __syncthreads();
    }

#pragma unroll
    for (int m = 0; m < 4; m++) {
        int row = m0 + wm * 64 + m * 16 + kg * 4;
        float cf[4];
#pragma unroll
        for (int r = 0; r < 4; r++) cf[r] = coef[(size_t)(row + r) * cstride];
#pragma unroll
        for (int n = 0; n < 4; n++) {
            int col = n0 + wn * 64 + n * 16 + lr;
#pragma unroll
            for (int r = 0; r < 4; r++) {
                float v = cf[r] * acc[m][n][r];
                float* o = &Out[(size_t)(row + r) * N + col];
                if (accum) *o += v; else *o = v;
            }
        }
    }
}

extern "C" void kernel_launch(void* const* d_in, const int* in_sizes, int n_in,
                              void* d_out, int out_size, void* d_ws, size_t ws_size,
                              hipStream_t stream)
{
    const float* x   = (const float*)d_in[0];
    const float* gw  = (const float*)d_in[1];
    const float* egw = (const float*)d_in[2];
    const float* euw = (const float*)d_in[3];
    const float* edw = (const float*)d_in[4];
    const float* sgp = (const float*)d_in[5];
    const float* sup = (const float*)d_in[6];
    const float* sdw = (const float*)d_in[7];
    const float* seg = (const float*)d_in[8];

    float* out0 = (float*)d_out;
    float* gate_out = out0 + (size_t)T_TOK * DDIM;

    char* ws = (char*)d_ws;
    unsigned short* xb   = (unsigned short*)ws; ws += (size_t)T_TOK * DDIM * 2;
    unsigned short* h    = (unsigned short*)ws; ws += (size_t)T_TOK * IDIM * 2;
    unsigned short* wg_t = (unsigned short*)ws; ws += (size_t)IDIM * DDIM * 2;
    unsigned short* wu_t = (unsigned short*)ws; ws += (size_t)IDIM * DDIM * 2;
    unsigned short* wd_t = (unsigned short*)ws; ws += (size_t)DDIM * IDIM * 2;
    float* wdense = (float*)ws; ws += (size_t)T_TOK * NEXP * 4;
    float* sgo    = (float*)ws; ws += (size_t)T_TOK * 4;

    router_kernel<<<T_TOK / 4, 256, 0, stream>>>(x, gw, seg, gate_out, wdense, sgo);
    cvt_kernel<<<(T_TOK * DDIM / 8) / 256, 256, 0, stream>>>(x, xb, T_TOK * DDIM / 8);

    // Shared expert first: writes out0 with '=' (clears stale data), sigmoid-gated.
    transcvt_kernel<<<dim3(IDIM / 64, DDIM / 64), 256, 0, stream>>>(sgp, wg_t, DDIM, IDIM);
    transcvt_kernel<<<dim3(IDIM / 64, DDIM / 64), 256, 0, stream>>>(sup, wu_t, DDIM, IDIM);
    transcvt_kernel<<<dim3(DDIM / 64, IDIM / 64), 256, 0, stream>>>(sdw, wd_t, IDIM, DDIM);
    gemm_gateup<<<dim3(IDIM / 128, T_TOK / 128), 256, 0, stream>>>(
        xb, wg_t, wu_t, h, T_TOK, IDIM, DDIM);
    gemm_down<<<dim3(DDIM / 128, T_TOK / 128), 256, 0, stream>>>(
        h, wd_t, out0, sgo, 1, 0, T_TOK, DDIM, IDIM);

    // Routed experts: dense compute, weight applied in epilogue (accumulate).
    for (int e = 0; e < NEXP; e++) {
        transcvt_kernel<<<dim3(IDIM / 64, DDIM / 64), 256, 0, stream>>>(
            egw + (size_t)e * DDIM * IDIM, wg_t, DDIM, IDIM);
        transcvt_kernel<<<dim3(IDIM / 64, DDIM / 64), 256, 0, stream>>>(
            euw + (size_t)e * DDIM * IDIM, wu_t, DDIM, IDIM);
        transcvt_kernel<<<dim3(DDIM / 64, IDIM / 64), 256, 0, stream>>>(
            edw + (size_t)e * IDIM * DDIM, wd_t, IDIM, DDIM);
        gemm_gateup<<<dim3(IDIM / 128, T_TOK / 128), 256, 0, stream>>>(
            xb, wg_t, wu_t, h, T_TOK, IDIM, DDIM);
        gemm_down<<<dim3(DDIM / 128, T_TOK / 128), 256, 0, stream>>>(
            h, wd_t, out0, wdense + e, NEXP, 1, T_TOK, DDIM, IDIM);
    }
}

// Round 2
// 1063.795 us; speedup vs baseline: 1.3569x; 1.3569x over previous
//
#include <hip/hip_runtime.h>

typedef __bf16 bf16x8 __attribute__((ext_vector_type(8)));
typedef float f32x4 __attribute__((ext_vector_type(4)));
typedef float f4 __attribute__((ext_vector_type(4)));
typedef unsigned short us8 __attribute__((ext_vector_type(8)));

#define T_TOK 8192
#define DDIM 1024
#define NEXP 8
#define IDIM 2048

__device__ __forceinline__ unsigned short f2bf(float f) {
    unsigned u = __float_as_uint(f);
    u += 0x7fffu + ((u >> 16) & 1u);   // round-to-nearest-even
    return (unsigned short)(u >> 16);
}

// ---------------- Router: gate logits (fp32), softmax/top2 dense weights, shared sigmoid gate ----------------
__global__ __launch_bounds__(256) void router_kernel(
    const float* __restrict__ x, const float* __restrict__ gate_w,
    const float* __restrict__ sgw, float* __restrict__ gate_out,
    float* __restrict__ wdense, float* __restrict__ sgout)
{
    __shared__ float lgw[DDIM * NEXP];
    __shared__ float lsg[DDIM];
    int tid = threadIdx.x;
    for (int i = tid; i < (DDIM * NEXP) / 4; i += 256)
        ((f4*)lgw)[i] = ((const f4*)gate_w)[i];
    for (int i = tid; i < DDIM / 4; i += 256)
        ((f4*)lsg)[i] = ((const f4*)sgw)[i];
    __syncthreads();

    int wid = tid >> 6, l = tid & 63;
    int t = blockIdx.x * 4 + wid;

    float acc[NEXP];
#pragma unroll
    for (int e = 0; e < NEXP; e++) acc[e] = 0.f;
    float accs = 0.f;
    const float* xr = x + (size_t)t * DDIM;
#pragma unroll
    for (int j = 0; j < 4; j++) {
        int d0 = j * 256 + l * 4;
        f4 xv = *(const f4*)(xr + d0);
#pragma unroll
        for (int c = 0; c < 4; c++) {
            float xd = xv[c];
            int d = d0 + c;
#pragma unroll
            for (int e = 0; e < NEXP; e++) acc[e] += xd * lgw[d * NEXP + e];
            accs += xd * lsg[d];
        }
    }
#pragma unroll
    for (int off = 32; off > 0; off >>= 1) {
#pragma unroll
        for (int e = 0; e < NEXP; e++) acc[e] += __shfl_xor(acc[e], off);
        accs += __shfl_xor(accs, off);
    }
    if (l == 0) {
        float m = acc[0];
        for (int e = 1; e < NEXP; e++) m = fmaxf(m, acc[e]);
        float p[NEXP], s = 0.f;
        for (int e = 0; e < NEXP; e++) { p[e] = __expf(acc[e] - m); s += p[e]; }
        float inv = 1.f / s;
        int i1 = 0; float b1 = p[0];
        for (int e = 1; e < NEXP; e++) if (p[e] > b1) { b1 = p[e]; i1 = e; }
        int i2 = -1; float b2 = -1.f;
        for (int e = 0; e < NEXP; e++) if (e != i1 && p[e] > b2) { b2 = p[e]; i2 = e; }
        for (int e = 0; e < NEXP; e++) {
            gate_out[(size_t)t * NEXP + e] = acc[e];
            float w = (e == i1) ? b1 * inv : (e == i2) ? b2 * inv : 0.f;
            wdense[(size_t)t * NEXP + e] = w;
        }
        sgout[t] = 1.f / (1.f + __expf(-accs));
    }
}

// ---------------- Deterministic per-expert token compaction (ballot scan, token order) ----------------
__global__ __launch_bounds__(256) void bucket_kernel(
    const float* __restrict__ wdense, int* __restrict__ list,
    float* __restrict__ wl, int* __restrict__ cnt)
{
    int e = blockIdx.x;
    int tid = threadIdx.x, wid = tid >> 6, l = tid & 63;
    __shared__ int wsum[4];
    int base = 0;
    int* le = list + (size_t)e * T_TOK;
    float* we = wl + (size_t)e * T_TOK;
    for (int t0 = 0; t0 < T_TOK; t0 += 256) {
        int tok = t0 + tid;
        float w = wdense[(size_t)tok * NEXP + e];
        bool f = w > 0.f;
        unsigned long long m = __ballot(f);
        int lp = __popcll(m & ((1ull << l) - 1ull));
        if (l == 0) wsum[wid] = __popcll(m);
        __syncthreads();
        int woff = 0;
#pragma unroll
        for (int i = 0; i < 4; i++) if (i < wid) woff += wsum[i];
        int btot = wsum[0] + wsum[1] + wsum[2] + wsum[3];
        if (f) { int pos = base + woff + lp; le[pos] = tok; we[pos] = w; }
        base += btot;
        __syncthreads();
    }
    if (tid == 0) cnt[e] = base;
    int align = (base + 127) & ~127;
    for (int i = base + tid; i < align; i += 256) { le[i] = 0; we[i] = 0.f; }
}

// ---------------- fp32 -> bf16 (same layout), 8 elems/thread ----------------
__global__ __launch_bounds__(256) void cvt_kernel(
    const float* __restrict__ in, unsigned short* __restrict__ out, int n8)
{
    int i = blockIdx.x * 256 + threadIdx.x;
    if (i >= n8) return;
    const f4* p = (const f4*)in + (size_t)i * 2;
    f4 a = p[0], b = p[1];
    us8 o;
#pragma unroll
    for (int k = 0; k < 4; k++) { o[k] = f2bf(a[k]); o[4 + k] = f2bf(b[k]); }
    *((us8*)out + i) = o;
}

// ---------------- fp32 [R,C] -> bf16 [C,R] transpose-convert, 64x64 LDS tiles ----------------
__global__ __launch_bounds__(256) void transcvt_kernel(
    const float* __restrict__ in, unsigned short* __restrict__ out, int R, int C)
{
    __shared__ unsigned short lds[64][72];
    int t = threadIdx.x;
    int c0 = blockIdx.x * 64, r0 = blockIdx.y * 64;
    int tr = t >> 4, tc = (t & 15) * 4;
#pragma unroll
    for (int j = 0; j < 4; j++) {
        int r = tr + j * 16;
        f4 v = *(const f4*)(in + (size_t)(r0 + r) * C + c0 + tc);
#pragma unroll
        for (int k = 0; k < 4; k++) lds[r][tc + k] = f2bf(v[k]);
    }
    __syncthreads();
    int orow = t >> 2, s = t & 3;
    us8 v0, v1;
#pragma unroll
    for (int i = 0; i < 8; i++) {
        v0[i] = lds[s * 16 + i][orow];
        v1[i] = lds[s * 16 + 8 + i][orow];
    }
    unsigned short* op = out + (size_t)(c0 + orow) * R + r0 + s * 16;
    *(us8*)op = v0;
    *(us8*)(op + 8) = v1;
}

// ---------------- GEMM staging helper: one 128x32 bf16 tile via global_load_lds ----------------
__device__ __forceinline__ void stage_tile(
    const unsigned short* __restrict__ g, int row0, int ldk, int k0,
    unsigned short* lds, int wid, int lane)
{
#pragma unroll
    for (int j = 0; j < 2; j++) {
        int c = wid + j * 4;              // chunk 0..7, 1KB each
        int seg = c * 64 + lane;          // seg = row*4 + kseg
        int row = seg >> 2, ks = seg & 3;
        const unsigned short* gp = g + (size_t)(row0 + row) * ldk + k0 + ks * 8;
        __builtin_amdgcn_global_load_lds(
            (const __attribute__((address_space(1))) void*)gp,
            (__attribute__((address_space(3))) void*)(lds + c * 512),
            16, 0, 0);
    }
}

// Fused gate+up GEMM with SwiGLU epilogue and optional row-gather on A:
// H[r,:] = silu(A[g(r),:]@Bg^T) * (A[g(r),:]@Bu^T), bf16 out (compacted rows).
__global__ __launch_bounds__(256, 2) void gemm_gateup(
    const unsigned short* __restrict__ A, const unsigned short* __restrict__ Bg,
    const unsigned short* __restrict__ Bu, unsigned short* __restrict__ H,
    const int* __restrict__ list, const int* __restrict__ cntp,
    int M, int N, int K)
{
    int m0 = blockIdx.y * 128, n0 = blockIdx.x * 128;
    int count = cntp ? *cntp : M;
    if (m0 >= count) return;

    __shared__ unsigned short As[128 * 32], Bgs[128 * 32], Bus[128 * 32];
    int tid = threadIdx.x, wid = tid >> 6, l = tid & 63;
    int wm = wid >> 1, wn = wid & 1;
    int lr = l & 15, kg = l >> 4;

    // A-row gather pointers (per-lane global source; LDS dest stays linear).
    int seg0 = wid * 64 + l, seg1 = (wid + 4) * 64 + l;
    int ra0 = seg0 >> 2, ka0 = seg0 & 3;
    int ra1 = seg1 >> 2, ka1 = seg1 & 3;
    int ga0 = list ? list[m0 + ra0] : (m0 + ra0);
    int ga1 = list ? list[m0 + ra1] : (m0 + ra1);
    const unsigned short* pa0 = A + (size_t)ga0 * K + ka0 * 8;
    const unsigned short* pa1 = A + (size_t)ga1 * K + ka1 * 8;

    f32x4 zero = {0.f, 0.f, 0.f, 0.f};
    f32x4 accg[4][4], accu[4][4];
#pragma unroll
    for (int m = 0; m < 4; m++)
#pragma unroll
        for (int n = 0; n < 4; n++) { accg[m][n] = zero; accu[m][n] = zero; }

    for (int k0 = 0; k0 < K; k0 += 32) {
        __builtin_amdgcn_global_load_lds(
            (const __attribute__((address_space(1))) void*)(pa0 + k0),
            (__attribute__((address_space(3))) void*)(As + wid * 512), 16, 0, 0);
        __builtin_amdgcn_global_load_lds(
            (const __attribute__((address_space(1))) void*)(pa1 + k0),
            (__attribute__((address_space(3))) void*)(As + (wid + 4) * 512), 16, 0, 0);
        stage_tile(Bg, n0, K, k0, Bgs, wid, l);
        stage_tile(Bu, n0, K, k0, Bus, wid, l);
        __syncthreads();
        bf16x8 a[4], bg[4], bu[4];
#pragma unroll
        for (int m = 0; m < 4; m++)
            a[m] = *(const bf16x8*)(As + ((wm * 64 + m * 16 + lr) * 32 + kg * 8));
#pragma unroll
        for (int n = 0; n < 4; n++) {
            bg[n] = *(const bf16x8*)(Bgs + ((wn * 64 + n * 16 + lr) * 32 + kg * 8));
            bu[n] = *(const bf16x8*)(Bus + ((wn * 64 + n * 16 + lr) * 32 + kg * 8));
        }
#pragma unroll
        for (int m = 0; m < 4; m++)
#pragma unroll
            for (int n = 0; n < 4; n++) {
                accg[m][n] = __builtin_amdgcn_mfma_f32_16x16x32_bf16(a[m], bg[n], accg[m][n], 0, 0, 0);
                accu[m][n] = __builtin_amdgcn_mfma_f32_16x16x32_bf16(a[m], bu[n], accu[m][n], 0, 0, 0);
            }
        __syncthreads();
    }

#pragma unroll
    for (int m = 0; m < 4; m++) {
        int row = m0 + wm * 64 + m * 16 + kg * 4;
#pragma unroll
        for (int n = 0; n < 4; n++) {
            int col = n0 + wn * 64 + n * 16 + lr;
#pragma unroll
            for (int r = 0; r < 4; r++) {
                float g = accg[m][n][r], u = accu[m][n][r];
                float hv = g * (1.f / (1.f + __expf(-g))) * u;
                H[(size_t)(row + r) * N + col] = f2bf(hv);
            }
        }
    }
}

// Down GEMM, compacted A, scatter-accumulate output:
// Out[list[r],:] (+)= coef[r] * (A[r,:]@B^T), rows r < count only.
__global__ __launch_bounds__(256, 2) void gemm_down(
    const unsigned short* __restrict__ A, const unsigned short* __restrict__ B,
    float* __restrict__ Out, const float* __restrict__ coefc,
    const int* __restrict__ list, const int* __restrict__ cntp,
    int accum, int M, int N, int K)
{
    int m0 = blockIdx.y * 128, n0 = blockIdx.x * 128;
    int count = cntp ? *cntp : M;
    if (m0 >= count) return;

    __shared__ unsigned short As[128 * 32], Bs[128 * 32];
    int tid = threadIdx.x, wid = tid >> 6, l = tid & 63;
    int wm = wid >> 1, wn = wid & 1;
    int lr = l & 15, kg = l >> 4;

    f32x4 zero = {0.f, 0.f, 0.f, 0.f};
    f32x4 acc[4][4];
#pragma unroll
    for (int m = 0; m < 4; m++)
#pragma unroll
        for (int n = 0; n < 4; n++) acc[m][n] = zero;

    for (int k0 = 0; k0 < K; k0 += 32) {
        stage_tile(A, m0, K, k0, As, wid, l);
        stage_tile(B, n0, K, k0, Bs, wid, l);
        __syncthreads();
        bf16x8 a[4], b[4];
#pragma unroll
        for (int m = 0; m < 4; m++)
            a[m] = *(const bf16x8*)(As + ((wm * 64 + m * 16 + lr) * 32 + kg * 8));
#pragma unroll
        for (int n = 0; n < 4; n++)
            b[n] = *(const bf16x8*)(Bs + ((wn * 64 + n * 16 + lr) * 32 + kg * 8));
#pragma unroll
        for (int m = 0; m < 4; m++)
#pragma unroll
            for (int n = 0; n < 4; n++)
                acc[m][n] = __builtin_amdgcn_mfma_f32_16x16x32_bf16(a[m], b[n], acc[m][n], 0, 0, 0);
        __syncthreads();
    }

#pragma unroll
    for (int m = 0; m < 4; m++) {
        int rowc = m0 + wm * 64 + m * 16 + kg * 4;
        int tg[4]; float cf[4];
#pragma unroll
        for (int r = 0; r < 4; r++) {
            int rc = rowc + r;
            bool ok = rc < count;
            tg[r] = ok ? (list ? list[rc] : rc) : -1;
            cf[r] = ok ? coefc[rc] : 0.f;
        }
#pragma unroll
        for (int n = 0; n < 4; n++) {
            int col = n0 + wn * 64 + n * 16 + lr;
#pragma unroll
            for (int r = 0; r < 4; r++) {
                if (tg[r] >= 0) {
                    float v = cf[r] * acc[m][n][r];
                    float* o = &Out[(size_t)tg[r] * N + col];
                    if (accum) *o += v; else *o = v;
                }
            }
        }
    }
}

extern "C" void kernel_launch(void* const* d_in, const int* in_sizes, int n_in,
                              void* d_out, int out_size, void* d_ws, size_t ws_size,
                              hipStream_t stream)
{
    const float* x   = (const float*)d_in[0];
    const float* gw  = (const float*)d_in[1];
    const float* egw = (const float*)d_in[2];
    const float* euw = (const float*)d_in[3];
    const float* edw = (const float*)d_in[4];
    const float* sgp = (const float*)d_in[5];
    const float* sup = (const float*)d_in[6];
    const float* sdw = (const float*)d_in[7];
    const float* seg = (const float*)d_in[8];

    float* out0 = (float*)d_out;
    float* gate_out = out0 + (size_t)T_TOK * DDIM;

    char* ws = (char*)d_ws;
    unsigned short* xb   = (unsigned short*)ws; ws += (size_t)T_TOK * DDIM * 2;
    unsigned short* h    = (unsigned short*)ws; ws += (size_t)T_TOK * IDIM * 2;
    unsigned short* wg_t = (unsigned short*)ws; ws += (size_t)IDIM * DDIM * 2;
    unsigned short* wu_t = (unsigned short*)ws; ws += (size_t)IDIM * DDIM * 2;
    unsigned short* wd_t = (unsigned short*)ws; ws += (size_t)DDIM * IDIM * 2;
    float* wdense = (float*)ws; ws += (size_t)T_TOK * NEXP * 4;
    float* sgo    = (float*)ws; ws += (size_t)T_TOK * 4;
    int*   list   = (int*)ws;   ws += (size_t)NEXP * T_TOK * 4;
    float* wl     = (float*)ws; ws += (size_t)NEXP * T_TOK * 4;
    int*   cnt    = (int*)ws;   ws += 64;

    router_kernel<<<T_TOK / 4, 256, 0, stream>>>(x, gw, seg, gate_out, wdense, sgo);
    bucket_kernel<<<NEXP, 256, 0, stream>>>(wdense, list, wl, cnt);
    cvt_kernel<<<(T_TOK * DDIM / 8) / 256, 256, 0, stream>>>(x, xb, T_TOK * DDIM / 8);

    // Shared expert first: writes out0 with '=' (clears stale data), sigmoid-gated.
    transcvt_kernel<<<dim3(IDIM / 64, DDIM / 64), 256, 0, stream>>>(sgp, wg_t, DDIM, IDIM);
    transcvt_kernel<<<dim3(IDIM / 64, DDIM / 64), 256, 0, stream>>>(sup, wu_t, DDIM, IDIM);
    transcvt_kernel<<<dim3(DDIM / 64, IDIM / 64), 256, 0, stream>>>(sdw, wd_t, IDIM, DDIM);
    gemm_gateup<<<dim3(IDIM / 128, T_TOK / 128), 256, 0, stream>>>(
        xb, wg_t, wu_t, h, nullptr, nullptr, T_TOK, IDIM, DDIM);
    gemm_down<<<dim3(DDIM / 128, T_TOK / 128), 256, 0, stream>>>(
        h, wd_t, out0, sgo, nullptr, nullptr, 0, T_TOK, DDIM, IDIM);

    // Routed experts: compacted tokens only, weight applied in scatter epilogue.
    for (int e = 0; e < NEXP; e++) {
        transcvt_kernel<<<dim3(IDIM / 64, DDIM / 64), 256, 0, stream>>>(
            egw + (size_t)e * DDIM * IDIM, wg_t, DDIM, IDIM);
        transcvt_kernel<<<dim3(IDIM / 64, DDIM / 64), 256, 0, stream>>>(
            euw + (size_t)e * DDIM * IDIM, wu_t, DDIM, IDIM);
        transcvt_kernel<<<dim3(DDIM / 64, IDIM / 64), 256, 0, stream>>>(
            edw + (size_t)e * IDIM * DDIM, wd_t, IDIM, DDIM);
        gemm_gateup<<<dim3(IDIM / 128, T_TOK / 128), 256, 0, stream>>>(
            xb, wg_t, wu_t, h, list + (size_t)e * T_TOK, cnt + e, T_TOK, IDIM, DDIM);
        gemm_down<<<dim3(DDIM / 128, T_TOK / 128), 256, 0, stream>>>(
            h, wd_t, out0, wl + (size_t)e * T_TOK, list + (size_t)e * T_TOK, cnt + e,
            1, T_TOK, DDIM, IDIM);
    }
}

// Round 4
// 632.593 us; speedup vs baseline: 2.2819x; 1.6816x over previous
//
#include <hip/hip_runtime.h>

typedef __bf16 bf16x8 __attribute__((ext_vector_type(8)));
typedef float f32x4 __attribute__((ext_vector_type(4)));
typedef float f4 __attribute__((ext_vector_type(4)));
typedef unsigned short us8 __attribute__((ext_vector_type(8)));

#define T_TOK 8192
#define DDIM 1024
#define NEXP 8
#define IDIM 2048
#define RROWS 17408                 // cap on sum of 128-aligned per-expert counts (<=16384+8*127)
#define ROWS_TOT (T_TOK + RROWS)    // 25600: shared rows [0,8192), routed rows at 8192+offs[e]

__device__ __forceinline__ unsigned short f2bf(float f) {
    unsigned u = __float_as_uint(f);
    u += 0x7fffu + ((u >> 16) & 1u);   // round-to-nearest-even
    return (unsigned short)(u >> 16);
}

// ---------------- Router: fp32 logits, softmax/top2 weights, shared sigmoid gate ----------------
__global__ __launch_bounds__(256) void router_kernel(
    const float* __restrict__ x, const float* __restrict__ gate_w,
    const float* __restrict__ sgw, float* __restrict__ gate_out,
    float* __restrict__ wdense, float* __restrict__ sgout)
{
    __shared__ float lgw[DDIM * NEXP];
    __shared__ float lsg[DDIM];
    int tid = threadIdx.x;
    for (int i = tid; i < (DDIM * NEXP) / 4; i += 256)
        ((f4*)lgw)[i] = ((const f4*)gate_w)[i];
    for (int i = tid; i < DDIM / 4; i += 256)
        ((f4*)lsg)[i] = ((const f4*)sgw)[i];
    __syncthreads();

    int wid = tid >> 6, l = tid & 63;
    int t = blockIdx.x * 4 + wid;

    float acc[NEXP];
#pragma unroll
    for (int e = 0; e < NEXP; e++) acc[e] = 0.f;
    float accs = 0.f;
    const float* xr = x + (size_t)t * DDIM;
#pragma unroll
    for (int j = 0; j < 4; j++) {
        int d0 = j * 256 + l * 4;
        f4 xv = *(const f4*)(xr + d0);
#pragma unroll
        for (int c = 0; c < 4; c++) {
            float xd = xv[c];
            int d = d0 + c;
#pragma unroll
            for (int e = 0; e < NEXP; e++) acc[e] += xd * lgw[d * NEXP + e];
            accs += xd * lsg[d];
        }
    }
#pragma unroll
    for (int off = 32; off > 0; off >>= 1) {
#pragma unroll
        for (int e = 0; e < NEXP; e++) acc[e] += __shfl_xor(acc[e], off);
        accs += __shfl_xor(accs, off);
    }
    if (l == 0) {
        float m = acc[0];
        for (int e = 1; e < NEXP; e++) m = fmaxf(m, acc[e]);
        float p[NEXP], s = 0.f;
        for (int e = 0; e < NEXP; e++) { p[e] = __expf(acc[e] - m); s += p[e]; }
        float inv = 1.f / s;
        int i1 = 0; float b1 = p[0];
        for (int e = 1; e < NEXP; e++) if (p[e] > b1) { b1 = p[e]; i1 = e; }
        int i2 = -1; float b2 = -1.f;
        for (int e = 0; e < NEXP; e++) if (e != i1 && p[e] > b2) { b2 = p[e]; i2 = e; }
        for (int e = 0; e < NEXP; e++) {
            gate_out[(size_t)t * NEXP + e] = acc[e];
            float w = (e == i1) ? b1 * inv : (e == i2) ? b2 * inv : 0.f;
            wdense[(size_t)t * NEXP + e] = w;
        }
        sgout[t] = 1.f / (1.f + __expf(-accs));
    }
}

// ---------------- Per-expert compaction + per-token (expert,pos,weight) maps ----------------
__global__ __launch_bounds__(256) void bucket_kernel(
    const float* __restrict__ wdense, int* __restrict__ list,
    float* __restrict__ wl, int* __restrict__ cnt,
    int* __restrict__ te, int* __restrict__ tp, float* __restrict__ tw)
{
    int e = blockIdx.x;
    int tid = threadIdx.x, wid = tid >> 6, l = tid & 63;
    __shared__ int wsum[4];
    int base = 0;
    int* le = list + (size_t)e * T_TOK;
    float* we = wl + (size_t)e * T_TOK;
    for (int t0 = 0; t0 < T_TOK; t0 += 256) {
        int tok = t0 + tid;
        float w = wdense[(size_t)tok * NEXP + e];
        bool f = w > 0.f;
        unsigned long long m = __ballot(f);
        int lp = __popcll(m & ((1ull << l) - 1ull));
        if (l == 0) wsum[wid] = __popcll(m);
        __syncthreads();
        int woff = 0;
#pragma unroll
        for (int i = 0; i < 4; i++) if (i < wid) woff += wsum[i];
        int btot = wsum[0] + wsum[1] + wsum[2] + wsum[3];
        if (f) {
            int pos = base + woff + lp;
            le[pos] = tok; we[pos] = w;
            int slot = 0;
            for (int e2 = 0; e2 < e; e2++)
                slot += (wdense[(size_t)tok * NEXP + e2] > 0.f) ? 1 : 0;
            te[tok * 2 + slot] = e;
            tp[tok * 2 + slot] = pos;
            tw[tok * 2 + slot] = w;
        }
        base += btot;
        __syncthreads();
    }
    if (tid == 0) cnt[e] = base;
    int align = (base + 127) & ~127;
    for (int i = base + tid; i < align; i += 256) { le[i] = 0; we[i] = 0.f; }
}

// ---------------- Exclusive scan of 128-aligned counts ----------------
__global__ void scan_kernel(const int* __restrict__ cnt, int* __restrict__ offs)
{
    if (threadIdx.x == 0) {
        int o = 0;
        for (int e = 0; e < NEXP; e++) { offs[e] = o; o += (cnt[e] + 127) & ~127; }
    }
}

// ---------------- fp32 -> bf16 same-layout ----------------
__global__ __launch_bounds__(256) void cvt_kernel(
    const float* __restrict__ in, unsigned short* __restrict__ out, int n8)
{
    int i = blockIdx.x * 256 + threadIdx.x;
    if (i >= n8) return;
    const f4* p = (const f4*)in + (size_t)i * 2;
    f4 a = p[0], b = p[1];
    us8 o;
#pragma unroll
    for (int k = 0; k < 4; k++) { o[k] = f2bf(a[k]); o[4 + k] = f2bf(b[k]); }
    *((us8*)out + i) = o;
}

// ---------------- Zero out the final output region (atomic mode) ----------------
__global__ __launch_bounds__(256) void zero_kernel(float* __restrict__ p, int n4)
{
    int i = blockIdx.x * 256 + threadIdx.x;
    if (i < n4) ((f4*)p)[i] = f4{0.f, 0.f, 0.f, 0.f};
}

// ---- wcvt gate/up: transpose chunk cols [c0,c0+NC) of [DDIM,IDIM] fp32 -> pool[j][NC][DDIM] bf16 ----
__global__ __launch_bounds__(256) void wcvt_gu_kernel(
    const float* __restrict__ egw, const float* __restrict__ euw,
    const float* __restrict__ sgp, const float* __restrict__ sup,
    unsigned short* __restrict__ pool, int c0, int NC)
{
    int j = blockIdx.y;                       // 0..17 = e*2+s, e=8 -> shared
    int e = j >> 1, s = j & 1;
    const float* src = (e < 8) ? ((s ? euw : egw) + (size_t)e * DDIM * IDIM)
                               : (s ? sup : sgp);
    unsigned short* dst = pool + (size_t)j * NC * DDIM;
    int tpc = NC / 64;
    int tci = blockIdx.x % tpc, tri = blockIdx.x / tpc;  // tri in [0,16)
    int r0 = tri * 64;                        // D row base
    int cl0 = tci * 64;                       // local I col base
    int cg0 = c0 + cl0;

    __shared__ unsigned short lds[64][72];
    int t = threadIdx.x;
    int tr = t >> 4, tcc = (t & 15) * 4;
#pragma unroll
    for (int jj = 0; jj < 4; jj++) {
        int r = tr + jj * 16;
        f4 v = *(const f4*)(src + (size_t)(r0 + r) * IDIM + cg0 + tcc);
#pragma unroll
        for (int k = 0; k < 4; k++) lds[r][tcc + k] = f2bf(v[k]);
    }
    __syncthreads();
    int orow = t >> 2, ss = t & 3;
    us8 v0, v1;
#pragma unroll
    for (int i = 0; i < 8; i++) {
        v0[i] = lds[ss * 16 + i][orow];
        v1[i] = lds[ss * 16 + 8 + i][orow];
    }
    unsigned short* op = dst + (size_t)(cl0 + orow) * DDIM + r0 + ss * 16;
    *(us8*)op = v0; *(us8*)(op + 8) = v1;
}

// ---- wcvt down: transpose chunk rows [c0,c0+NC) of [IDIM,DDIM] fp32 -> pool[j][DDIM][NC] bf16 ----
__global__ __launch_bounds__(256) void wcvt_d_kernel(
    const float* __restrict__ edw, const float* __restrict__ sdw,
    unsigned short* __restrict__ pool, int c0, int NC)
{
    int j = blockIdx.y;                       // 0..8, 8 -> shared
    const float* src = (j < 8) ? edw + (size_t)j * IDIM * DDIM : sdw;  // [I, D]
    unsigned short* dst = pool + (size_t)j * DDIM * NC;                // [D][NC]
    int tpc = DDIM / 64;                      // 16
    int tci = blockIdx.x % tpc, tri = blockIdx.x / tpc;  // tri in [0,NC/64)
    int rl0 = tri * 64;                       // local I row base
    int rg0 = c0 + rl0;
    int cg0 = tci * 64;                       // D col base

    __shared__ unsigned short lds[64][72];
    int t = threadIdx.x;
    int tr = t >> 4, tcc = (t & 15) * 4;
#pragma unroll
    for (int jj = 0; jj < 4; jj++) {
        int r = tr + jj * 16;
        f4 v = *(const f4*)(src + (size_t)(rg0 + r) * DDIM + cg0 + tcc);
#pragma unroll
        for (int k = 0; k < 4; k++) lds[r][tcc + k] = f2bf(v[k]);
    }
    __syncthreads();
    int orow = t >> 2, ss = t & 3;
    us8 v0, v1;
#pragma unroll
    for (int i = 0; i < 8; i++) {
        v0[i] = lds[ss * 16 + i][orow];
        v1[i] = lds[ss * 16 + 8 + i][orow];
    }
    unsigned short* op = dst + (size_t)(cg0 + orow) * NC + rl0 + ss * 16;
    *(us8*)op = v0; *(us8*)(op + 8) = v1;
}

// ---------------- GEMM staging helper (128 rows x 32 k bf16 tile) ----------------
__device__ __forceinline__ void stage_tile(
    const unsigned short* __restrict__ g, int row0, int ldk, int k0,
    unsigned short* lds, int wid, int lane)
{
#pragma unroll
    for (int j = 0; j < 2; j++) {
        int c = wid + j * 4;
        int seg = c * 64 + lane;
        int row = seg >> 2, ks = seg & 3;
        const unsigned short* gp = g + (size_t)(row0 + row) * ldk + k0 + ks * 8;
        __builtin_amdgcn_global_load_lds(
            (const __attribute__((address_space(1))) void*)gp,
            (__attribute__((address_space(3))) void*)(lds + c * 512),
            16, 0, 0);
    }
}

// ---------------- Batched gate+up GEMM + SwiGLU, I-chunked (z=0 shared, z=1..8 routed) ----------------
__global__ __launch_bounds__(256, 2) void gemm_gateup(
    const unsigned short* __restrict__ A, const unsigned short* __restrict__ pool,
    unsigned short* __restrict__ H, const int* __restrict__ listb,
    const int* __restrict__ cnt, const int* __restrict__ offs, int NC)
{
    int z = blockIdx.z;
    const unsigned short *Bg, *Bu; const int* lst; int count, rowb;
    if (z == 0) {
        Bg = pool + (size_t)16 * NC * DDIM; Bu = pool + (size_t)17 * NC * DDIM;
        lst = nullptr; count = T_TOK; rowb = 0;
    } else {
        int e = z - 1;
        Bg = pool + (size_t)(e * 2) * NC * DDIM; Bu = pool + (size_t)(e * 2 + 1) * NC * DDIM;
        lst = listb + (size_t)e * T_TOK; count = cnt[e]; rowb = T_TOK + offs[e];
    }
    const int K = DDIM;
    int m0 = blockIdx.y * 128, n0 = blockIdx.x * 128;
    if (m0 >= count) return;

    __shared__ unsigned short As[128 * 32], Bgs[128 * 32], Bus[128 * 32];
    int tid = threadIdx.x, wid = tid >> 6, l = tid & 63;
    int wm = wid >> 1, wn = wid & 1;
    int lr = l & 15, kg = l >> 4;

    int seg0 = wid * 64 + l, seg1 = (wid + 4) * 64 + l;
    int ra0 = seg0 >> 2, ka0 = seg0 & 3;
    int ra1 = seg1 >> 2, ka1 = seg1 & 3;
    int ga0 = lst ? lst[m0 + ra0] : (m0 + ra0);
    int ga1 = lst ? lst[m0 + ra1] : (m0 + ra1);
    const unsigned short* pa0 = A + (size_t)ga0 * K + ka0 * 8;
    const unsigned short* pa1 = A + (size_t)ga1 * K + ka1 * 8;

    f32x4 zero = {0.f, 0.f, 0.f, 0.f};
    f32x4 accg[4][4], accu[4][4];
#pragma unroll
    for (int m = 0; m < 4; m++)
#pragma unroll
        for (int n = 0; n < 4; n++) { accg[m][n] = zero; accu[m][n] = zero; }

    for (int k0 = 0; k0 < K; k0 += 32) {
        __builtin_amdgcn_global_load_lds(
            (const __attribute__((address_space(1))) void*)(pa0 + k0),
            (__attribute__((address_space(3))) void*)(As + wid * 512), 16, 0, 0);
        __builtin_amdgcn_global_load_lds(
            (const __attribute__((address_space(1))) void*)(pa1 + k0),
            (__attribute__((address_space(3))) void*)(As + (wid + 4) * 512), 16, 0, 0);
        stage_tile(Bg, n0, K, k0, Bgs, wid, l);
        stage_tile(Bu, n0, K, k0, Bus, wid, l);
        __syncthreads();
        bf16x8 a[4], bg[4], bu[4];
#pragma unroll
        for (int m = 0; m < 4; m++)
            a[m] = *(const bf16x8*)(As + ((wm * 64 + m * 16 + lr) * 32 + kg * 8));
#pragma unroll
        for (int n = 0; n < 4; n++) {
            bg[n] = *(const bf16x8*)(Bgs + ((wn * 64 + n * 16 + lr) * 32 + kg * 8));
            bu[n] = *(const bf16x8*)(Bus + ((wn * 64 + n * 16 + lr) * 32 + kg * 8));
        }
#pragma unroll
        for (int m = 0; m < 4; m++)
#pragma unroll
            for (int n = 0; n < 4; n++) {
                accg[m][n] = __builtin_amdgcn_mfma_f32_16x16x32_bf16(a[m], bg[n], accg[m][n], 0, 0, 0);
                accu[m][n] = __builtin_amdgcn_mfma_f32_16x16x32_bf16(a[m], bu[n], accu[m][n], 0, 0, 0);
            }
        __syncthreads();
    }

#pragma unroll
    for (int m = 0; m < 4; m++) {
        int row = rowb + m0 + wm * 64 + m * 16 + kg * 4;
#pragma unroll
        for (int n = 0; n < 4; n++) {
            int col = n0 + wn * 64 + n * 16 + lr;
#pragma unroll
            for (int r = 0; r < 4; r++) {
                float g = accg[m][n][r], u = accu[m][n][r];
                float hv = g * (1.f / (1.f + __expf(-g))) * u;
                H[(size_t)(row + r) * NC + col] = f2bf(hv);
            }
        }
    }
}

// ---------------- Batched down GEMM, K = NC chunk ----------------
// MODE 0: Y[row] = acc     MODE 1: Y[row] += acc     MODE 2: atomicAdd(out[tok], coef*acc)
template<int MODE>
__global__ __launch_bounds__(256, 2) void gemm_down(
    const unsigned short* __restrict__ H, const unsigned short* __restrict__ pool,
    float* __restrict__ Y, float* __restrict__ out0,
    const float* __restrict__ wlb, const float* __restrict__ sgo,
    const int* __restrict__ listb, const int* __restrict__ cnt,
    const int* __restrict__ offs, int NC)
{
    int z = blockIdx.z;
    const unsigned short* B; const int* lst; const float* coef; int count, rowb;
    if (z == 0) {
        B = pool + (size_t)8 * DDIM * NC;
        lst = nullptr; coef = sgo; count = T_TOK; rowb = 0;
    } else {
        int e = z - 1;
        B = pool + (size_t)e * DDIM * NC;
        lst = listb + (size_t)e * T_TOK; coef = wlb + (size_t)e * T_TOK;
        count = cnt[e]; rowb = T_TOK + offs[e];
    }
    int m0 = blockIdx.y * 128, n0 = blockIdx.x * 128;
    if (m0 >= count) return;
    const unsigned short* Arows = H + (size_t)rowb * NC;

    __shared__ unsigned short As[128 * 32], Bs[128 * 32];
    int tid = threadIdx.x, wid = tid >> 6, l = tid & 63;
    int wm = wid >> 1, wn = wid & 1;
    int lr = l & 15, kg = l >> 4;

    f32x4 zero = {0.f, 0.f, 0.f, 0.f};
    f32x4 acc[4][4];
#pragma unroll
    for (int m = 0; m < 4; m++)
#pragma unroll
        for (int n = 0; n < 4; n++) acc[m][n] = zero;

    for (int k0 = 0; k0 < NC; k0 += 32) {
        stage_tile(Arows, m0, NC, k0, As, wid, l);
        stage_tile(B, n0, NC, k0, Bs, wid, l);
        __syncthreads();
        bf16x8 a[4], b[4];
#pragma unroll
        for (int m = 0; m < 4; m++)
            a[m] = *(const bf16x8*)(As + ((wm * 64 + m * 16 + lr) * 32 + kg * 8));
#pragma unroll
        for (int n = 0; n < 4; n++)
            b[n] = *(const bf16x8*)(Bs + ((wn * 64 + n * 16 + lr) * 32 + kg * 8));
#pragma unroll
        for (int m = 0; m < 4; m++)
#pragma unroll
            for (int n = 0; n < 4; n++)
                acc[m][n] = __builtin_amdgcn_mfma_f32_16x16x32_bf16(a[m], b[n], acc[m][n], 0, 0, 0);
        __syncthreads();
    }

#pragma unroll
    for (int m = 0; m < 4; m++) {
        int rloc = m0 + wm * 64 + m * 16 + kg * 4;
#pragma unroll
        for (int n = 0; n < 4; n++) {
            int col = n0 + wn * 64 + n * 16 + lr;
#pragma unroll
            for (int r = 0; r < 4; r++) {
                float v = acc[m][n][r];
                if (MODE == 0) {
                    Y[(size_t)(rowb + rloc + r) * DDIM + col] = v;
                } else if (MODE == 1) {
                    Y[(size_t)(rowb + rloc + r) * DDIM + col] += v;
                } else {
                    int rc = rloc + r;
                    if (rc < count) {
                        int tok = lst ? lst[rc] : rc;
                        atomicAdd(&out0[(size_t)tok * DDIM + col], coef[rc] * v);
                    }
                }
            }
        }
    }
}

// ---------------- Combine (Y-mode): out = sgo*Y[t] + w0*Y[r0] + w1*Y[r1] ----------------
__global__ __launch_bounds__(256) void combine_kernel(
    const float* __restrict__ Y, const float* __restrict__ sgo,
    const int* __restrict__ te, const int* __restrict__ tp,
    const float* __restrict__ tw, const int* __restrict__ offs,
    float* __restrict__ out)
{
    int t = blockIdx.x * 2 + (threadIdx.x >> 7);
    int c = (threadIdx.x & 127) * 8;
    int e0 = te[2 * t], e1 = te[2 * t + 1];
    size_t r0 = (size_t)T_TOK + offs[e0] + tp[2 * t];
    size_t r1 = (size_t)T_TOK + offs[e1] + tp[2 * t + 1];
    float w0 = tw[2 * t], w1 = tw[2 * t + 1], sg = sgo[t];

    const float* ys = Y + (size_t)t * DDIM + c;
    const float* y0 = Y + r0 * DDIM + c;
    const float* y1 = Y + r1 * DDIM + c;
    f4 s0 = *(const f4*)ys, s1 = *(const f4*)(ys + 4);
    f4 a0 = *(const f4*)y0, a1 = *(const f4*)(y0 + 4);
    f4 b0 = *(const f4*)y1, b1 = *(const f4*)(y1 + 4);
    f4 o0, o1;
#pragma unroll
    for (int k = 0; k < 4; k++) {
        o0[k] = sg * s0[k] + w0 * a0[k] + w1 * b0[k];
        o1[k] = sg * s1[k] + w0 * a1[k] + w1 * b1[k];
    }
    float* op = out + (size_t)t * DDIM + c;
    *(f4*)op = o0;
    *(f4*)(op + 4) = o1;
}

extern "C" void kernel_launch(void* const* d_in, const int* in_sizes, int n_in,
                              void* d_out, int out_size, void* d_ws, size_t ws_size,
                              hipStream_t stream)
{
    const float* x   = (const float*)d_in[0];
    const float* gw  = (const float*)d_in[1];
    const float* egw = (const float*)d_in[2];
    const float* euw = (const float*)d_in[3];
    const float* edw = (const float*)d_in[4];
    const float* sgp = (const float*)d_in[5];
    const float* sup = (const float*)d_in[6];
    const float* sdw = (const float*)d_in[7];
    const float* seg = (const float*)d_in[8];

    float* out0 = (float*)d_out;
    float* gate_out = out0 + (size_t)T_TOK * DDIM;

    auto al = [](size_t b) { return (b + 255) & ~(size_t)255; };
    size_t fixed_b = al((size_t)T_TOK * DDIM * 2)            // xb
                   + al((size_t)T_TOK * NEXP * 4)            // wdense
                   + al((size_t)T_TOK * 4)                   // sgo
                   + al((size_t)NEXP * T_TOK * 4)            // list
                   + al((size_t)NEXP * T_TOK * 4)            // wl
                   + 256 + 256                               // cnt, offs
                   + 3 * al((size_t)T_TOK * 2 * 4);          // te, tp, tw
    auto pool_b = [&](int NC) { return al((size_t)18 * NC * DDIM * 2); };
    auto h_b    = [&](int NC) { return al((size_t)ROWS_TOT * NC * 2); };
    size_t y_b  = al((size_t)ROWS_TOT * DDIM * 4);

    // Tier selection (ws_size is constant across calls -> deterministic).
    int ISPLIT; bool ymode;
    if (fixed_b + pool_b(1024) + h_b(1024) + y_b <= ws_size)      { ISPLIT = 2; ymode = true;  }
    else if (fixed_b + pool_b(1024) + h_b(1024) <= ws_size)       { ISPLIT = 2; ymode = false; }
    else if (fixed_b + pool_b(512) + h_b(512) <= ws_size)         { ISPLIT = 4; ymode = false; }
    else                                                          { ISPLIT = 8; ymode = false; }
    int NC = IDIM / ISPLIT;

    char* ws = (char*)d_ws;
    auto take = [&](size_t bytes) { char* p = ws; ws += (bytes + 255) & ~(size_t)255; return p; };
    unsigned short* xb   = (unsigned short*)take((size_t)T_TOK * DDIM * 2);
    float* wdense = (float*)take((size_t)T_TOK * NEXP * 4);
    float* sgo    = (float*)take((size_t)T_TOK * 4);
    int*   list   = (int*)take((size_t)NEXP * T_TOK * 4);
    float* wl     = (float*)take((size_t)NEXP * T_TOK * 4);
    int*   cnt    = (int*)take(0); ws += 256;
    int*   offs   = (int*)take(0); ws += 256;
    int*   te     = (int*)take((size_t)T_TOK * 2 * 4);
    int*   tp     = (int*)take((size_t)T_TOK * 2 * 4);
    float* tw     = (float*)take((size_t)T_TOK * 2 * 4);
    unsigned short* pool = (unsigned short*)take((size_t)18 * NC * DDIM * 2);
    unsigned short* H    = (unsigned short*)take((size_t)ROWS_TOT * NC * 2);
    float* Y = ymode ? (float*)take((size_t)ROWS_TOT * DDIM * 4) : nullptr;

    router_kernel<<<T_TOK / 4, 256, 0, stream>>>(x, gw, seg, gate_out, wdense, sgo);
    bucket_kernel<<<NEXP, 256, 0, stream>>>(wdense, list, wl, cnt, te, tp, tw);
    scan_kernel<<<1, 64, 0, stream>>>(cnt, offs);
    cvt_kernel<<<(T_TOK * DDIM / 8) / 256, 256, 0, stream>>>(x, xb, T_TOK * DDIM / 8);
    if (!ymode)
        zero_kernel<<<(T_TOK * DDIM / 4) / 256, 256, 0, stream>>>(out0, T_TOK * DDIM / 4);

    for (int c = 0; c < ISPLIT; c++) {
        int c0 = c * NC;
        wcvt_gu_kernel<<<dim3((NC / 64) * 16, 18), 256, 0, stream>>>(
            egw, euw, sgp, sup, pool, c0, NC);
        gemm_gateup<<<dim3(NC / 128, T_TOK / 128, 9), 256, 0, stream>>>(
            xb, pool, H, list, cnt, offs, NC);
        wcvt_d_kernel<<<dim3((NC / 64) * 16, 9), 256, 0, stream>>>(
            edw, sdw, pool, c0, NC);
        if (ymode) {
            if (c == 0)
                gemm_down<0><<<dim3(DDIM / 128, T_TOK / 128, 9), 256, 0, stream>>>(
                    H, pool, Y, out0, wl, sgo, list, cnt, offs, NC);
            else
                gemm_down<1><<<dim3(DDIM / 128, T_TOK / 128, 9), 256, 0, stream>>>(
                    H, pool, Y, out0, wl, sgo, list, cnt, offs, NC);
        } else {
            gemm_down<2><<<dim3(DDIM / 128, T_TOK / 128, 9), 256, 0, stream>>>(
                H, pool, Y, out0, wl, sgo, list, cnt, offs, NC);
        }
    }
    if (ymode)
        combine_kernel<<<T_TOK / 2, 256, 0, stream>>>(Y, sgo, te, tp, tw, offs, out0);
}

// Round 5
// 590.802 us; speedup vs baseline: 2.4433x; 1.0707x over previous
//
#include <hip/hip_runtime.h>

typedef __bf16 bf16x8 __attribute__((ext_vector_type(8)));
typedef float f32x4 __attribute__((ext_vector_type(4)));
typedef float f4 __attribute__((ext_vector_type(4)));
typedef unsigned short us8 __attribute__((ext_vector_type(8)));

#define T_TOK 8192
#define DDIM 1024
#define NEXP 8
#define IDIM 2048
#define NCH 1024                    // gateup N-chunk (weight pool half)
#define RROWS 17408                 // cap on sum of 128-aligned per-expert counts
#define ROWS_TOT (T_TOK + RROWS)    // 25600 rows: shared [0,8192), routed at 8192+offs[e]

__device__ __forceinline__ unsigned short f2bf(float f) {
    unsigned u = __float_as_uint(f);
    u += 0x7fffu + ((u >> 16) & 1u);   // round-to-nearest-even
    return (unsigned short)(u >> 16);
}

// ---------------- Router: fp32 logits, softmax/top2 weights, shared sigmoid gate ----------------
__global__ __launch_bounds__(256) void router_kernel(
    const float* __restrict__ x, const float* __restrict__ gate_w,
    const float* __restrict__ sgw, float* __restrict__ gate_out,
    float* __restrict__ wdense, float* __restrict__ sgout)
{
    __shared__ float lgw[DDIM * NEXP];
    __shared__ float lsg[DDIM];
    int tid = threadIdx.x;
    for (int i = tid; i < (DDIM * NEXP) / 4; i += 256)
        ((f4*)lgw)[i] = ((const f4*)gate_w)[i];
    for (int i = tid; i < DDIM / 4; i += 256)
        ((f4*)lsg)[i] = ((const f4*)sgw)[i];
    __syncthreads();

    int wid = tid >> 6, l = tid & 63;
    int t = blockIdx.x * 4 + wid;

    float acc[NEXP];
#pragma unroll
    for (int e = 0; e < NEXP; e++) acc[e] = 0.f;
    float accs = 0.f;
    const float* xr = x + (size_t)t * DDIM;
#pragma unroll
    for (int j = 0; j < 4; j++) {
        int d0 = j * 256 + l * 4;
        f4 xv = *(const f4*)(xr + d0);
#pragma unroll
        for (int c = 0; c < 4; c++) {
            float xd = xv[c];
            int d = d0 + c;
#pragma unroll
            for (int e = 0; e < NEXP; e++) acc[e] += xd * lgw[d * NEXP + e];
            accs += xd * lsg[d];
        }
    }
#pragma unroll
    for (int off = 32; off > 0; off >>= 1) {
#pragma unroll
        for (int e = 0; e < NEXP; e++) acc[e] += __shfl_xor(acc[e], off);
        accs += __shfl_xor(accs, off);
    }
    if (l == 0) {
        float m = acc[0];
        for (int e = 1; e < NEXP; e++) m = fmaxf(m, acc[e]);
        float p[NEXP], s = 0.f;
        for (int e = 0; e < NEXP; e++) { p[e] = __expf(acc[e] - m); s += p[e]; }
        float inv = 1.f / s;
        int i1 = 0; float b1 = p[0];
        for (int e = 1; e < NEXP; e++) if (p[e] > b1) { b1 = p[e]; i1 = e; }
        int i2 = -1; float b2 = -1.f;
        for (int e = 0; e < NEXP; e++) if (e != i1 && p[e] > b2) { b2 = p[e]; i2 = e; }
        for (int e = 0; e < NEXP; e++) {
            gate_out[(size_t)t * NEXP + e] = acc[e];
            float w = (e == i1) ? b1 * inv : (e == i2) ? b2 * inv : 0.f;
            wdense[(size_t)t * NEXP + e] = w;
        }
        sgout[t] = 1.f / (1.f + __expf(-accs));
    }
}

// ---------------- Per-expert compaction + per-token (expert,pos) maps ----------------
__global__ __launch_bounds__(256) void bucket_kernel(
    const float* __restrict__ wdense, int* __restrict__ list,
    float* __restrict__ wl, int* __restrict__ cnt,
    int* __restrict__ te, int* __restrict__ tp)
{
    int e = blockIdx.x;
    int tid = threadIdx.x, wid = tid >> 6, l = tid & 63;
    __shared__ int wsum[4];
    int base = 0;
    int* le = list + (size_t)e * T_TOK;
    float* we = wl + (size_t)e * T_TOK;
    for (int t0 = 0; t0 < T_TOK; t0 += 256) {
        int tok = t0 + tid;
        float w = wdense[(size_t)tok * NEXP + e];
        bool f = w > 0.f;
        unsigned long long m = __ballot(f);
        int lp = __popcll(m & ((1ull << l) - 1ull));
        if (l == 0) wsum[wid] = __popcll(m);
        __syncthreads();
        int woff = 0;
#pragma unroll
        for (int i = 0; i < 4; i++) if (i < wid) woff += wsum[i];
        int btot = wsum[0] + wsum[1] + wsum[2] + wsum[3];
        if (f) {
            int pos = base + woff + lp;
            le[pos] = tok; we[pos] = w;
            int slot = 0;
            for (int e2 = 0; e2 < e; e2++)
                slot += (wdense[(size_t)tok * NEXP + e2] > 0.f) ? 1 : 0;
            te[tok * 2 + slot] = e;
            tp[tok * 2 + slot] = pos;
        }
        base += btot;
        __syncthreads();
    }
    if (tid == 0) cnt[e] = base;
    int align = (base + 127) & ~127;
    for (int i = base + tid; i < align; i += 256) { le[i] = 0; we[i] = 0.f; }
}

// ---------------- Exclusive scan of 128-aligned counts ----------------
__global__ void scan_kernel(const int* __restrict__ cnt, int* __restrict__ offs)
{
    if (threadIdx.x == 0) {
        int o = 0;
        for (int e = 0; e < NEXP; e++) { offs[e] = o; o += (cnt[e] + 127) & ~127; }
    }
}

// ---------------- fp32 -> bf16 same-layout ----------------
__global__ __launch_bounds__(256) void cvt_kernel(
    const float* __restrict__ in, unsigned short* __restrict__ out, int n8)
{
    int i = blockIdx.x * 256 + threadIdx.x;
    if (i >= n8) return;
    const f4* p = (const f4*)in + (size_t)i * 2;
    f4 a = p[0], b = p[1];
    us8 o;
#pragma unroll
    for (int k = 0; k < 4; k++) { o[k] = f2bf(a[k]); o[4 + k] = f2bf(b[k]); }
    *((us8*)out + i) = o;
}

// ---- wcvt gate/up: transpose chunk cols [c0,c0+NCH) of [DDIM,IDIM] fp32 -> pool[j][NCH][DDIM] bf16 ----
__global__ __launch_bounds__(256) void wcvt_gu_kernel(
    const float* __restrict__ egw, const float* __restrict__ euw,
    const float* __restrict__ sgp, const float* __restrict__ sup,
    unsigned short* __restrict__ pool, int c0)
{
    int j = blockIdx.y;                       // 0..17 = e*2+s, e=8 -> shared
    int e = j >> 1, s = j & 1;
    const float* src = (e < 8) ? ((s ? euw : egw) + (size_t)e * DDIM * IDIM)
                               : (s ? sup : sgp);
    unsigned short* dst = pool + (size_t)j * NCH * DDIM;
    int tpc = NCH / 64;
    int tci = blockIdx.x % tpc, tri = blockIdx.x / tpc;
    int r0 = tri * 64;                        // D row base
    int cl0 = tci * 64;                       // local I col base
    int cg0 = c0 + cl0;

    __shared__ unsigned short lds[64][72];
    int t = threadIdx.x;
    int tr = t >> 4, tcc = (t & 15) * 4;
#pragma unroll
    for (int jj = 0; jj < 4; jj++) {
        int r = tr + jj * 16;
        f4 v = *(const f4*)(src + (size_t)(r0 + r) * IDIM + cg0 + tcc);
#pragma unroll
        for (int k = 0; k < 4; k++) lds[r][tcc + k] = f2bf(v[k]);
    }
    __syncthreads();
    int orow = t >> 2, ss = t & 3;
    us8 v0, v1;
#pragma unroll
    for (int i = 0; i < 8; i++) {
        v0[i] = lds[ss * 16 + i][orow];
        v1[i] = lds[ss * 16 + 8 + i][orow];
    }
    unsigned short* op = dst + (size_t)(cl0 + orow) * DDIM + r0 + ss * 16;
    *(us8*)op = v0; *(us8*)(op + 8) = v1;
}

// ---- wcvt down: full transpose [IDIM,DDIM] fp32 -> pool[j][DDIM][IDIM] bf16 ----
__global__ __launch_bounds__(256) void wcvt_d_kernel(
    const float* __restrict__ edw, const float* __restrict__ sdw,
    unsigned short* __restrict__ pool)
{
    int j = blockIdx.y;                       // 0..8, 8 -> shared
    const float* src = (j < 8) ? edw + (size_t)j * IDIM * DDIM : sdw;  // [I, D]
    unsigned short* dst = pool + (size_t)j * DDIM * IDIM;              // [D][I]
    int tpc = DDIM / 64;                      // 16
    int tci = blockIdx.x % tpc, tri = blockIdx.x / tpc;
    int rg0 = tri * 64;                       // I row base
    int cg0 = tci * 64;                       // D col base

    __shared__ unsigned short lds[64][72];
    int t = threadIdx.x;
    int tr = t >> 4, tcc = (t & 15) * 4;
#pragma unroll
    for (int jj = 0; jj < 4; jj++) {
        int r = tr + jj * 16;
        f4 v = *(const f4*)(src + (size_t)(rg0 + r) * DDIM + cg0 + tcc);
#pragma unroll
        for (int k = 0; k < 4; k++) lds[r][tcc + k] = f2bf(v[k]);
    }
    __syncthreads();
    int orow = t >> 2, ss = t & 3;
    us8 v0, v1;
#pragma unroll
    for (int i = 0; i < 8; i++) {
        v0[i] = lds[ss * 16 + i][orow];
        v1[i] = lds[ss * 16 + 8 + i][orow];
    }
    unsigned short* op = dst + (size_t)(cg0 + orow) * IDIM + rg0 + ss * 16;
    *(us8*)op = v0; *(us8*)(op + 8) = v1;
}

// ---------------- GEMM staging helper (128 rows x 32 k bf16 tile) ----------------
__device__ __forceinline__ void stage_tile(
    const unsigned short* __restrict__ g, int row0, int ldk, int k0,
    unsigned short* lds, int wid, int lane)
{
#pragma unroll
    for (int j = 0; j < 2; j++) {
        int c = wid + j * 4;
        int seg = c * 64 + lane;
        int row = seg >> 2, ks = seg & 3;
        const unsigned short* gp = g + (size_t)(row0 + row) * ldk + k0 + ks * 8;
        __builtin_amdgcn_global_load_lds(
            (const __attribute__((address_space(1))) void*)gp,
            (__attribute__((address_space(3))) void*)(lds + c * 512),
            16, 0, 0);
    }
}

// ---------------- Batched gate+up GEMM + SwiGLU (z=0 shared, z=1..8 routed) ----------------
// Grid (8, 64, 9): XCD-pinned N-panels via nt = flat%8 (round-robin dispatch -> each XCD
// keeps its B panel (0.5 MB) hot in L2 across all 64 M-blocks).
__global__ __launch_bounds__(256, 2) void gemm_gateup(
    const unsigned short* __restrict__ A, const unsigned short* __restrict__ pool,
    unsigned short* __restrict__ H, const int* __restrict__ listb,
    const int* __restrict__ cnt, const int* __restrict__ offs, int c0)
{
    int z = blockIdx.z;
    const unsigned short *Bg, *Bu; const int* lst; int count, rowb;
    if (z == 0) {
        Bg = pool + (size_t)16 * NCH * DDIM; Bu = pool + (size_t)17 * NCH * DDIM;
        lst = nullptr; count = T_TOK; rowb = 0;
    } else {
        int e = z - 1;
        Bg = pool + (size_t)(e * 2) * NCH * DDIM; Bu = pool + (size_t)(e * 2 + 1) * NCH * DDIM;
        lst = listb + (size_t)e * T_TOK; count = cnt[e]; rowb = T_TOK + offs[e];
    }
    int flat = blockIdx.y * 8 + blockIdx.x;   // nwg = 512
    int nt = flat & 7, mt = flat >> 3;
    int m0 = mt * 128, n0 = nt * 128;
    if (m0 >= count) return;
    const int K = DDIM;

    __shared__ unsigned short As[128 * 32], Bgs[128 * 32], Bus[128 * 32];
    int tid = threadIdx.x, wid = tid >> 6, l = tid & 63;
    int wm = wid >> 1, wn = wid & 1;
    int lr = l & 15, kg = l >> 4;

    int seg0 = wid * 64 + l, seg1 = (wid + 4) * 64 + l;
    int ra0 = seg0 >> 2, ka0 = seg0 & 3;
    int ra1 = seg1 >> 2, ka1 = seg1 & 3;
    int ga0 = lst ? lst[m0 + ra0] : (m0 + ra0);
    int ga1 = lst ? lst[m0 + ra1] : (m0 + ra1);
    const unsigned short* pa0 = A + (size_t)ga0 * K + ka0 * 8;
    const unsigned short* pa1 = A + (size_t)ga1 * K + ka1 * 8;

    f32x4 zero = {0.f, 0.f, 0.f, 0.f};
    f32x4 accg[4][4], accu[4][4];
#pragma unroll
    for (int m = 0; m < 4; m++)
#pragma unroll
        for (int n = 0; n < 4; n++) { accg[m][n] = zero; accu[m][n] = zero; }

    for (int k0 = 0; k0 < K; k0 += 32) {
        __builtin_amdgcn_global_load_lds(
            (const __attribute__((address_space(1))) void*)(pa0 + k0),
            (__attribute__((address_space(3))) void*)(As + wid * 512), 16, 0, 0);
        __builtin_amdgcn_global_load_lds(
            (const __attribute__((address_space(1))) void*)(pa1 + k0),
            (__attribute__((address_space(3))) void*)(As + (wid + 4) * 512), 16, 0, 0);
        stage_tile(Bg, n0, K, k0, Bgs, wid, l);
        stage_tile(Bu, n0, K, k0, Bus, wid, l);
        __syncthreads();
        bf16x8 a[4], bg[4], bu[4];
#pragma unroll
        for (int m = 0; m < 4; m++)
            a[m] = *(const bf16x8*)(As + ((wm * 64 + m * 16 + lr) * 32 + kg * 8));
#pragma unroll
        for (int n = 0; n < 4; n++) {
            bg[n] = *(const bf16x8*)(Bgs + ((wn * 64 + n * 16 + lr) * 32 + kg * 8));
            bu[n] = *(const bf16x8*)(Bus + ((wn * 64 + n * 16 + lr) * 32 + kg * 8));
        }
#pragma unroll
        for (int m = 0; m < 4; m++)
#pragma unroll
            for (int n = 0; n < 4; n++) {
                accg[m][n] = __builtin_amdgcn_mfma_f32_16x16x32_bf16(a[m], bg[n], accg[m][n], 0, 0, 0);
                accu[m][n] = __builtin_amdgcn_mfma_f32_16x16x32_bf16(a[m], bu[n], accu[m][n], 0, 0, 0);
            }
        __syncthreads();
    }

#pragma unroll
    for (int m = 0; m < 4; m++) {
        int row = rowb + m0 + wm * 64 + m * 16 + kg * 4;
#pragma unroll
        for (int n = 0; n < 4; n++) {
            int col = c0 + n0 + wn * 64 + n * 16 + lr;
#pragma unroll
            for (int r = 0; r < 4; r++) {
                float g = accg[m][n][r], u = accu[m][n][r];
                float hv = g * (1.f / (1.f + __expf(-g))) * u;
                H[(size_t)(row + r) * IDIM + col] = f2bf(hv);
            }
        }
    }
}

// ---------------- Batched down GEMM, K=IDIM, coef applied in epilogue, bf16 Y ----------------
__global__ __launch_bounds__(256, 2) void gemm_down(
    const unsigned short* __restrict__ H, const unsigned short* __restrict__ pool,
    unsigned short* __restrict__ Y,
    const float* __restrict__ wlb, const float* __restrict__ sgo,
    const int* __restrict__ cnt, const int* __restrict__ offs)
{
    int z = blockIdx.z;
    const unsigned short* B; const float* coef; int count, rowb;
    if (z == 0) {
        B = pool + (size_t)8 * DDIM * IDIM;
        coef = sgo; count = T_TOK; rowb = 0;
    } else {
        int e = z - 1;
        B = pool + (size_t)e * DDIM * IDIM;
        coef = wlb + (size_t)e * T_TOK;
        count = cnt[e]; rowb = T_TOK + offs[e];
    }
    int flat = blockIdx.y * 8 + blockIdx.x;   // nwg = 512
    int nt = flat & 7, mt = flat >> 3;
    int m0 = mt * 128, n0 = nt * 128;
    if (m0 >= count) return;
    const unsigned short* Arows = H + (size_t)rowb * IDIM;

    __shared__ unsigned short As[128 * 32], Bs[128 * 32];
    int tid = threadIdx.x, wid = tid >> 6, l = tid & 63;
    int wm = wid >> 1, wn = wid & 1;
    int lr = l & 15, kg = l >> 4;

    f32x4 zero = {0.f, 0.f, 0.f, 0.f};
    f32x4 acc[4][4];
#pragma unroll
    for (int m = 0; m < 4; m++)
#pragma unroll
        for (int n = 0; n < 4; n++) acc[m][n] = zero;

    for (int k0 = 0; k0 < IDIM; k0 += 32) {
        stage_tile(Arows, m0, IDIM, k0, As, wid, l);
        stage_tile(B, n0, IDIM, k0, Bs, wid, l);
        __syncthreads();
        bf16x8 a[4], b[4];
#pragma unroll
        for (int m = 0; m < 4; m++)
            a[m] = *(const bf16x8*)(As + ((wm * 64 + m * 16 + lr) * 32 + kg * 8));
#pragma unroll
        for (int n = 0; n < 4; n++)
            b[n] = *(const bf16x8*)(Bs + ((wn * 64 + n * 16 + lr) * 32 + kg * 8));
#pragma unroll
        for (int m = 0; m < 4; m++)
#pragma unroll
            for (int n = 0; n < 4; n++)
                acc[m][n] = __builtin_amdgcn_mfma_f32_16x16x32_bf16(a[m], b[n], acc[m][n], 0, 0, 0);
        __syncthreads();
    }

#pragma unroll
    for (int m = 0; m < 4; m++) {
        int rloc = m0 + wm * 64 + m * 16 + kg * 4;
        float cf[4];
#pragma unroll
        for (int r = 0; r < 4; r++) cf[r] = coef[rloc + r];   // pads have coef 0
#pragma unroll
        for (int n = 0; n < 4; n++) {
            int col = n0 + wn * 64 + n * 16 + lr;
#pragma unroll
            for (int r = 0; r < 4; r++)
                Y[(size_t)(rowb + rloc + r) * DDIM + col] = f2bf(cf[r] * acc[m][n][r]);
        }
    }
}

// ---------------- Combine: out[t] = Y[t] + Y[r0] + Y[r1] (weights pre-applied) ----------------
__global__ __launch_bounds__(256) void combine_kernel(
    const unsigned short* __restrict__ Y, const int* __restrict__ te,
    const int* __restrict__ tp, const int* __restrict__ offs,
    float* __restrict__ out)
{
    int t = blockIdx.x * 2 + (threadIdx.x >> 7);
    int c = (threadIdx.x & 127) * 8;
    int e0 = te[2 * t], e1 = te[2 * t + 1];
    size_t r0 = (size_t)T_TOK + offs[e0] + tp[2 * t];
    size_t r1 = (size_t)T_TOK + offs[e1] + tp[2 * t + 1];

    us8 vs = *(const us8*)(Y + (size_t)t * DDIM + c);
    us8 v0 = *(const us8*)(Y + r0 * DDIM + c);
    us8 v1 = *(const us8*)(Y + r1 * DDIM + c);
    f4 o0, o1;
#pragma unroll
    for (int k = 0; k < 4; k++) {
        o0[k] = __uint_as_float((unsigned)vs[k] << 16)
              + __uint_as_float((unsigned)v0[k] << 16)
              + __uint_as_float((unsigned)v1[k] << 16);
        o1[k] = __uint_as_float((unsigned)vs[4 + k] << 16)
              + __uint_as_float((unsigned)v0[4 + k] << 16)
              + __uint_as_float((unsigned)v1[4 + k] << 16);
    }
    float* op = out + (size_t)t * DDIM + c;
    *(f4*)op = o0;
    *(f4*)(op + 4) = o1;
}

extern "C" void kernel_launch(void* const* d_in, const int* in_sizes, int n_in,
                              void* d_out, int out_size, void* d_ws, size_t ws_size,
                              hipStream_t stream)
{
    const float* x   = (const float*)d_in[0];
    const float* gw  = (const float*)d_in[1];
    const float* egw = (const float*)d_in[2];
    const float* euw = (const float*)d_in[3];
    const float* edw = (const float*)d_in[4];
    const float* sgp = (const float*)d_in[5];
    const float* sup = (const float*)d_in[6];
    const float* sdw = (const float*)d_in[7];
    const float* seg = (const float*)d_in[8];

    float* out0 = (float*)d_out;
    float* gate_out = out0 + (size_t)T_TOK * DDIM;

    // Workspace layout: identical 212,828,672-byte footprint to the round-4
    // passing configuration (pool 37.75 MB, H now full-stride 104.86 MB,
    // Y now bf16 52.43 MB).
    char* ws = (char*)d_ws;
    auto take = [&](size_t bytes) { char* p = ws; ws += (bytes + 255) & ~(size_t)255; return p; };
    unsigned short* xb   = (unsigned short*)take((size_t)T_TOK * DDIM * 2);
    float* wdense = (float*)take((size_t)T_TOK * NEXP * 4);
    float* sgo    = (float*)take((size_t)T_TOK * 4);
    int*   list   = (int*)take((size_t)NEXP * T_TOK * 4);
    float* wl     = (float*)take((size_t)NEXP * T_TOK * 4);
    int*   cnt    = (int*)take(256);
    int*   offs   = (int*)take(256);
    int*   te     = (int*)take((size_t)T_TOK * 2 * 4);
    int*   tp     = (int*)take((size_t)T_TOK * 2 * 4);
    unsigned short* pool = (unsigned short*)take((size_t)18 * NCH * DDIM * 2);
    unsigned short* H    = (unsigned short*)take((size_t)ROWS_TOT * IDIM * 2);
    unsigned short* Y    = (unsigned short*)take((size_t)ROWS_TOT * DDIM * 2);

    router_kernel<<<T_TOK / 4, 256, 0, stream>>>(x, gw, seg, gate_out, wdense, sgo);
    bucket_kernel<<<NEXP, 256, 0, stream>>>(wdense, list, wl, cnt, te, tp);
    scan_kernel<<<1, 64, 0, stream>>>(cnt, offs);
    cvt_kernel<<<(T_TOK * DDIM / 8) / 256, 256, 0, stream>>>(x, xb, T_TOK * DDIM / 8);

    // Gate+up in two N-chunks (weight pool reuse; H columns are independent).
    for (int c = 0; c < 2; c++) {
        int c0 = c * NCH;
        wcvt_gu_kernel<<<dim3((NCH / 64) * 16, 18), 256, 0, stream>>>(
            egw, euw, sgp, sup, pool, c0);
        gemm_gateup<<<dim3(8, 64, 9), 256, 0, stream>>>(
            xb, pool, H, list, cnt, offs, c0);
    }

    // Down: single pass, K = IDIM, combine weights folded into the epilogue.
    wcvt_d_kernel<<<dim3((IDIM / 64) * 16, 9), 256, 0, stream>>>(edw, sdw, pool);
    gemm_down<<<dim3(8, 64, 9), 256, 0, stream>>>(H, pool, Y, wl, sgo, cnt, offs);

    combine_kernel<<<T_TOK / 2, 256, 0, stream>>>(Y, te, tp, offs, out0);
}

// Round 6
// 552.022 us; speedup vs baseline: 2.6149x; 1.0703x over previous
//
#include <hip/hip_runtime.h>

typedef __bf16 bf16x8 __attribute__((ext_vector_type(8)));
typedef float f32x4 __attribute__((ext_vector_type(4)));
typedef float f4 __attribute__((ext_vector_type(4)));
typedef unsigned short us8 __attribute__((ext_vector_type(8)));

#define T_TOK 8192
#define DDIM 1024
#define NEXP 8
#define IDIM 2048
#define NCH 1024                    // gateup N-chunk (weight pool half)
#define RROWS 17408                 // cap on sum of 128-aligned per-expert counts
#define ROWS_TOT (T_TOK + RROWS)    // 25600 rows: shared [0,8192), routed at 8192+offs[e]

__device__ __forceinline__ unsigned short f2bf(float f) {
    unsigned u = __float_as_uint(f);
    u += 0x7fffu + ((u >> 16) & 1u);   // round-to-nearest-even
    return (unsigned short)(u >> 16);
}

#define GLDS(src, dst) __builtin_amdgcn_global_load_lds( \
    (const __attribute__((address_space(1))) void*)(src), \
    (__attribute__((address_space(3))) void*)(dst), 16, 0, 0)

// ---------------- Router ----------------
__global__ __launch_bounds__(256) void router_kernel(
    const float* __restrict__ x, const float* __restrict__ gate_w,
    const float* __restrict__ sgw, float* __restrict__ gate_out,
    float* __restrict__ wdense, float* __restrict__ sgout)
{
    __shared__ float lgw[DDIM * NEXP];
    __shared__ float lsg[DDIM];
    int tid = threadIdx.x;
    for (int i = tid; i < (DDIM * NEXP) / 4; i += 256)
        ((f4*)lgw)[i] = ((const f4*)gate_w)[i];
    for (int i = tid; i < DDIM / 4; i += 256)
        ((f4*)lsg)[i] = ((const f4*)sgw)[i];
    __syncthreads();

    int wid = tid >> 6, l = tid & 63;
    int t = blockIdx.x * 4 + wid;

    float acc[NEXP];
#pragma unroll
    for (int e = 0; e < NEXP; e++) acc[e] = 0.f;
    float accs = 0.f;
    const float* xr = x + (size_t)t * DDIM;
#pragma unroll
    for (int j = 0; j < 4; j++) {
        int d0 = j * 256 + l * 4;
        f4 xv = *(const f4*)(xr + d0);
#pragma unroll
        for (int c = 0; c < 4; c++) {
            float xd = xv[c];
            int d = d0 + c;
#pragma unroll
            for (int e = 0; e < NEXP; e++) acc[e] += xd * lgw[d * NEXP + e];
            accs += xd * lsg[d];
        }
    }
#pragma unroll
    for (int off = 32; off > 0; off >>= 1) {
#pragma unroll
        for (int e = 0; e < NEXP; e++) acc[e] += __shfl_xor(acc[e], off);
        accs += __shfl_xor(accs, off);
    }
    if (l == 0) {
        float m = acc[0];
        for (int e = 1; e < NEXP; e++) m = fmaxf(m, acc[e]);
        float p[NEXP], s = 0.f;
        for (int e = 0; e < NEXP; e++) { p[e] = __expf(acc[e] - m); s += p[e]; }
        float inv = 1.f / s;
        int i1 = 0; float b1 = p[0];
        for (int e = 1; e < NEXP; e++) if (p[e] > b1) { b1 = p[e]; i1 = e; }
        int i2 = -1; float b2 = -1.f;
        for (int e = 0; e < NEXP; e++) if (e != i1 && p[e] > b2) { b2 = p[e]; i2 = e; }
        for (int e = 0; e < NEXP; e++) {
            gate_out[(size_t)t * NEXP + e] = acc[e];
            float w = (e == i1) ? b1 * inv : (e == i2) ? b2 * inv : 0.f;
            wdense[(size_t)t * NEXP + e] = w;
        }
        sgout[t] = 1.f / (1.f + __expf(-accs));
    }
}

// ---------------- Per-expert compaction (pads to 256-alignment for BM=256 tiles) ----------------
__global__ __launch_bounds__(256) void bucket_kernel(
    const float* __restrict__ wdense, int* __restrict__ list,
    float* __restrict__ wl, int* __restrict__ cnt,
    int* __restrict__ te, int* __restrict__ tp)
{
    int e = blockIdx.x;
    int tid = threadIdx.x, wid = tid >> 6, l = tid & 63;
    __shared__ int wsum[4];
    int base = 0;
    int* le = list + (size_t)e * T_TOK;
    float* we = wl + (size_t)e * T_TOK;
    for (int t0 = 0; t0 < T_TOK; t0 += 256) {
        int tok = t0 + tid;
        float w = wdense[(size_t)tok * NEXP + e];
        bool f = w > 0.f;
        unsigned long long m = __ballot(f);
        int lp = __popcll(m & ((1ull << l) - 1ull));
        if (l == 0) wsum[wid] = __popcll(m);
        __syncthreads();
        int woff = 0;
#pragma unroll
        for (int i = 0; i < 4; i++) if (i < wid) woff += wsum[i];
        int btot = wsum[0] + wsum[1] + wsum[2] + wsum[3];
        if (f) {
            int pos = base + woff + lp;
            le[pos] = tok; we[pos] = w;
            int slot = 0;
            for (int e2 = 0; e2 < e; e2++)
                slot += (wdense[(size_t)tok * NEXP + e2] > 0.f) ? 1 : 0;
            te[tok * 2 + slot] = e;
            tp[tok * 2 + slot] = pos;
        }
        base += btot;
        __syncthreads();
    }
    if (tid == 0) cnt[e] = base;
    int align = (base + 255) & ~255;          // 256-pad: BM=256 tiles stay in-bounds
    for (int i = base + tid; i < align; i += 256) { le[i] = 0; we[i] = 0.f; }
}

// ---------------- Exclusive scan of 128-aligned counts ----------------
__global__ void scan_kernel(const int* __restrict__ cnt, int* __restrict__ offs)
{
    if (threadIdx.x == 0) {
        int o = 0;
        for (int e = 0; e < NEXP; e++) { offs[e] = o; o += (cnt[e] + 127) & ~127; }
    }
}

// ---------------- fp32 -> bf16 same-layout ----------------
__global__ __launch_bounds__(256) void cvt_kernel(
    const float* __restrict__ in, unsigned short* __restrict__ out, int n8)
{
    int i = blockIdx.x * 256 + threadIdx.x;
    if (i >= n8) return;
    const f4* p = (const f4*)in + (size_t)i * 2;
    f4 a = p[0], b = p[1];
    us8 o;
#pragma unroll
    for (int k = 0; k < 4; k++) { o[k] = f2bf(a[k]); o[4 + k] = f2bf(b[k]); }
    *((us8*)out + i) = o;
}

// ---- wcvt gate/up: transpose chunk cols [c0,c0+NCH) of [DDIM,IDIM] fp32 -> pool[j][NCH][DDIM] bf16 ----
__global__ __launch_bounds__(256) void wcvt_gu_kernel(
    const float* __restrict__ egw, const float* __restrict__ euw,
    const float* __restrict__ sgp, const float* __restrict__ sup,
    unsigned short* __restrict__ pool, int c0)
{
    int j = blockIdx.y;
    int e = j >> 1, s = j & 1;
    const float* src = (e < 8) ? ((s ? euw : egw) + (size_t)e * DDIM * IDIM)
                               : (s ? sup : sgp);
    unsigned short* dst = pool + (size_t)j * NCH * DDIM;
    int tpc = NCH / 64;
    int tci = blockIdx.x % tpc, tri = blockIdx.x / tpc;
    int r0 = tri * 64;
    int cl0 = tci * 64;
    int cg0 = c0 + cl0;

    __shared__ unsigned short lds[64][72];
    int t = threadIdx.x;
    int tr = t >> 4, tcc = (t & 15) * 4;
#pragma unroll
    for (int jj = 0; jj < 4; jj++) {
        int r = tr + jj * 16;
        f4 v = *(const f4*)(src + (size_t)(r0 + r) * IDIM + cg0 + tcc);
#pragma unroll
        for (int k = 0; k < 4; k++) lds[r][tcc + k] = f2bf(v[k]);
    }
    __syncthreads();
    int orow = t >> 2, ss = t & 3;
    us8 v0, v1;
#pragma unroll
    for (int i = 0; i < 8; i++) {
        v0[i] = lds[ss * 16 + i][orow];
        v1[i] = lds[ss * 16 + 8 + i][orow];
    }
    unsigned short* op = dst + (size_t)(cl0 + orow) * DDIM + r0 + ss * 16;
    *(us8*)op = v0; *(us8*)(op + 8) = v1;
}

// ---- wcvt down: full transpose [IDIM,DDIM] fp32 -> pool[j][DDIM][IDIM] bf16 ----
__global__ __launch_bounds__(256) void wcvt_d_kernel(
    const float* __restrict__ edw, const float* __restrict__ sdw,
    unsigned short* __restrict__ pool)
{
    int j = blockIdx.y;
    const float* src = (j < 8) ? edw + (size_t)j * IDIM * DDIM : sdw;
    unsigned short* dst = pool + (size_t)j * DDIM * IDIM;
    int tpc = DDIM / 64;
    int tci = blockIdx.x % tpc, tri = blockIdx.x / tpc;
    int rg0 = tri * 64;
    int cg0 = tci * 64;

    __shared__ unsigned short lds[64][72];
    int t = threadIdx.x;
    int tr = t >> 4, tcc = (t & 15) * 4;
#pragma unroll
    for (int jj = 0; jj < 4; jj++) {
        int r = tr + jj * 16;
        f4 v = *(const f4*)(src + (size_t)(rg0 + r) * DDIM + cg0 + tcc);
#pragma unroll
        for (int k = 0; k < 4; k++) lds[r][tcc + k] = f2bf(v[k]);
    }
    __syncthreads();
    int orow = t >> 2, ss = t & 3;
    us8 v0, v1;
#pragma unroll
    for (int i = 0; i < 8; i++) {
        v0[i] = lds[ss * 16 + i][orow];
        v1[i] = lds[ss * 16 + 8 + i][orow];
    }
    unsigned short* op = dst + (size_t)(cg0 + orow) * IDIM + rg0 + ss * 16;
    *(us8*)op = v0; *(us8*)(op + 8) = v1;
}

// =====================================================================
// 8-phase 256-tile gate+up GEMM + SwiGLU.  BM=256, BN=128, BK=64.
// 8 waves (4M x 2N), per-wave 64x64 dual (gate+up) output.
// LDS/buf: A[256][64] @0, Bg[128][64] @16384, Bu[128][64] @24576 elems.
// Swizzle: elem k ^= (row&7)<<3 on ds_read; inverse-swizzled global source.
// =====================================================================
__global__ __launch_bounds__(512, 2) void gemm_gateup8(
    const unsigned short* __restrict__ A, const unsigned short* __restrict__ pool,
    unsigned short* __restrict__ H, const int* __restrict__ listb,
    const int* __restrict__ cnt, const int* __restrict__ offs, int c0)
{
    int z = blockIdx.z;
    const unsigned short *Bg, *Bu; const int* lst; int count, rowb;
    if (z == 0) {
        Bg = pool + (size_t)16 * NCH * DDIM; Bu = pool + (size_t)17 * NCH * DDIM;
        lst = nullptr; count = T_TOK; rowb = 0;
    } else {
        int e = z - 1;
        Bg = pool + (size_t)(e * 2) * NCH * DDIM; Bu = pool + (size_t)(e * 2 + 1) * NCH * DDIM;
        lst = listb + (size_t)e * T_TOK; count = cnt[e]; rowb = T_TOK + offs[e];
    }
    int m0 = blockIdx.y * 256, n0 = blockIdx.x * 128;
    if (m0 >= count) return;
    int climit = (count + 127) & ~127;
    const int NT = DDIM / 64;   // 16

    __shared__ unsigned short lds[2][32768];   // 128 KiB

    int tid = threadIdx.x, wid = tid >> 6, l = tid & 63;
    int wm = wid >> 1, wn = wid & 1;           // wm 0..3, wn 0..1
    int lr = l & 15, lkg = l >> 4;

    // ---- staging source pointers (inverse-swizzled k) ----
    int sb = tid & 7, sr = tid >> 3;           // sr 0..63
    int sk = (sb ^ (sr & 7)) << 3;
    const unsigned short* pa[2][2];
#pragma unroll
    for (int h = 0; h < 2; h++)
#pragma unroll
        for (int j = 0; j < 2; j++) {
            int rr = m0 + h * 128 + j * 64 + sr;   // list padded to 256-align -> defined
            int ga = lst ? lst[rr] : rr;
            pa[h][j] = A + (size_t)ga * DDIM + sk;
        }
    const unsigned short* pbg = Bg + (size_t)(n0 + sr) * DDIM + sk;
    const unsigned short* pbu = Bu + (size_t)(n0 + sr) * DDIM + sk;

#define GU_ST_A(sbuf, h, t) { \
    GLDS(pa[h][0] + (t) * 64, (sbuf) + (h) * 8192 + tid * 8); \
    GLDS(pa[h][1] + (t) * 64, (sbuf) + (h) * 8192 + 4096 + tid * 8); }
#define GU_ST_BG(sbuf, t) { \
    GLDS(pbg + (t) * 64, (sbuf) + 16384 + tid * 8); \
    GLDS(pbg + (size_t)64 * DDIM + (t) * 64, (sbuf) + 16384 + 4096 + tid * 8); }
#define GU_ST_BU(sbuf, t) { \
    GLDS(pbu + (t) * 64, (sbuf) + 24576 + tid * 8); \
    GLDS(pbu + (size_t)64 * DDIM + (t) * 64, (sbuf) + 24576 + 4096 + tid * 8); }

    // prologue: t0 -> buf0, t1 -> buf1 (16 loads/thread outstanding)
    {
        unsigned short* s0 = &lds[0][0];
        GU_ST_A(s0, 0, 0); GU_ST_A(s0, 1, 0); GU_ST_BG(s0, 0); GU_ST_BU(s0, 0);
        unsigned short* s1 = &lds[1][0];
        GU_ST_A(s1, 0, 1); GU_ST_A(s1, 1, 1); GU_ST_BG(s1, 1); GU_ST_BU(s1, 1);
    }

    // ---- fragment LDS offsets (swizzled reads) ----
    int xorc = (lr & 7) << 3;
    int kx0 = (lkg * 8) ^ xorc;
    int kx1 = (32 + lkg * 8) ^ xorc;
    int aoff[4], boff[4];
#pragma unroll
    for (int mf = 0; mf < 4; mf++) {
        int r = wm * 64 + mf * 16 + lr;
        aoff[mf] = (r >> 7) * 8192 + (r & 127) * 64;
    }
#pragma unroll
    for (int nf = 0; nf < 4; nf++)
        boff[nf] = 16384 + (wn * 64 + nf * 16 + lr) * 64;

    f32x4 zero = {0.f, 0.f, 0.f, 0.f};
    f32x4 accg[4][4], accu[4][4];
#pragma unroll
    for (int m = 0; m < 4; m++)
#pragma unroll
        for (int n = 0; n < 4; n++) { accg[m][n] = zero; accu[m][n] = zero; }

    bf16x8 a[2][2], bg[4][2], bu[4][2];

#pragma unroll 1
    for (int t = 0; t < NT; t++) {
        const unsigned short* cb = &lds[t & 1][0];
        unsigned short* sbuf = &lds[t & 1][0];
        bool stg = (t + 2 < NT);

        // ---- P1: quadrant (mh0, nh0) ----
        if (t == NT - 1) { asm volatile("s_waitcnt vmcnt(0)" ::: "memory"); }
        else             { asm volatile("s_waitcnt vmcnt(8)" ::: "memory"); }
        __builtin_amdgcn_s_barrier();
#pragma unroll
        for (int mf = 0; mf < 2; mf++) {
            a[mf][0] = *(const bf16x8*)(cb + aoff[mf] + kx0);
            a[mf][1] = *(const bf16x8*)(cb + aoff[mf] + kx1);
        }
#pragma unroll
        for (int nf = 0; nf < 2; nf++) {
            bg[nf][0] = *(const bf16x8*)(cb + boff[nf] + kx0);
            bg[nf][1] = *(const bf16x8*)(cb + boff[nf] + kx1);
            bu[nf][0] = *(const bf16x8*)(cb + boff[nf] + 8192 + kx0);
            bu[nf][1] = *(const bf16x8*)(cb + boff[nf] + 8192 + kx1);
        }
        __builtin_amdgcn_s_setprio(1);
#pragma unroll
        for (int kh = 0; kh < 2; kh++)
#pragma unroll
            for (int mf = 0; mf < 2; mf++)
#pragma unroll
                for (int nf = 0; nf < 2; nf++) {
                    accg[mf][nf] = __builtin_amdgcn_mfma_f32_16x16x32_bf16(a[mf][kh], bg[nf][kh], accg[mf][nf], 0, 0, 0);
                    accu[mf][nf] = __builtin_amdgcn_mfma_f32_16x16x32_bf16(a[mf][kh], bu[nf][kh], accu[mf][nf], 0, 0, 0);
                }
        __builtin_amdgcn_s_setprio(0);

        // ---- P2: (mh0, nh1) ----
        __builtin_amdgcn_s_barrier();
#pragma unroll
        for (int nf = 2; nf < 4; nf++) {
            bg[nf][0] = *(const bf16x8*)(cb + boff[nf] + kx0);
            bg[nf][1] = *(const bf16x8*)(cb + boff[nf] + kx1);
            bu[nf][0] = *(const bf16x8*)(cb + boff[nf] + 8192 + kx0);
            bu[nf][1] = *(const bf16x8*)(cb + boff[nf] + 8192 + kx1);
        }
        __builtin_amdgcn_s_setprio(1);
#pragma unroll
        for (int kh = 0; kh < 2; kh++)
#pragma unroll
            for (int mf = 0; mf < 2; mf++)
#pragma unroll
                for (int nf = 2; nf < 4; nf++) {
                    accg[mf][nf] = __builtin_amdgcn_mfma_f32_16x16x32_bf16(a[mf][kh], bg[nf][kh], accg[mf][nf], 0, 0, 0);
                    accu[mf][nf] = __builtin_amdgcn_mfma_f32_16x16x32_bf16(a[mf][kh], bu[nf][kh], accu[mf][nf], 0, 0, 0);
                }
        __builtin_amdgcn_s_setprio(0);

        // ---- P3: (mh1, nh0); stage Bg(t+2) ----
        __builtin_amdgcn_s_barrier();
#pragma unroll
        for (int mf = 0; mf < 2; mf++) {
            a[mf][0] = *(const bf16x8*)(cb + aoff[2 + mf] + kx0);
            a[mf][1] = *(const bf16x8*)(cb + aoff[2 + mf] + kx1);
        }
        if (stg) { GU_ST_BG(sbuf, t + 2); }
        __builtin_amdgcn_s_setprio(1);
#pragma unroll
        for (int kh = 0; kh < 2; kh++)
#pragma unroll
            for (int mf = 0; mf < 2; mf++)
#pragma unroll
                for (int nf = 0; nf < 2; nf++) {
                    accg[2 + mf][nf] = __builtin_amdgcn_mfma_f32_16x16x32_bf16(a[mf][kh], bg[nf][kh], accg[2 + mf][nf], 0, 0, 0);
                    accu[2 + mf][nf] = __builtin_amdgcn_mfma_f32_16x16x32_bf16(a[mf][kh], bu[nf][kh], accu[2 + mf][nf], 0, 0, 0);
                }
        __builtin_amdgcn_s_setprio(0);

        // ---- P4: (mh1, nh1); stage Bu, A0, A1 (t+2) ----
        __builtin_amdgcn_s_barrier();
        if (stg) { GU_ST_BU(sbuf, t + 2); GU_ST_A(sbuf, 0, t + 2); GU_ST_A(sbuf, 1, t + 2); }
        __builtin_amdgcn_s_setprio(1);
#pragma unroll
        for (int kh = 0; kh < 2; kh++)
#pragma unroll
            for (int mf = 0; mf < 2; mf++)
#pragma unroll
                for (int nf = 2; nf < 4; nf++) {
                    accg[2 + mf][nf] = __builtin_amdgcn_mfma_f32_16x16x32_bf16(a[mf][kh], bg[nf][kh], accg[2 + mf][nf], 0, 0, 0);
                    accu[2 + mf][nf] = __builtin_amdgcn_mfma_f32_16x16x32_bf16(a[mf][kh], bu[nf][kh], accu[2 + mf][nf], 0, 0, 0);
                }
        __builtin_amdgcn_s_setprio(0);
    }

    // ---- epilogue: SwiGLU, guarded writes ----
#pragma unroll
    for (int mf = 0; mf < 4; mf++) {
        int rbase = m0 + wm * 64 + mf * 16 + lkg * 4;
#pragma unroll
        for (int nf = 0; nf < 4; nf++) {
            int col = c0 + n0 + wn * 64 + nf * 16 + lr;
#pragma unroll
            for (int r = 0; r < 4; r++) {
                int rloc = rbase + r;
                if (rloc < climit) {
                    float g = accg[mf][nf][r], u = accu[mf][nf][r];
                    float hv = g * (1.f / (1.f + __expf(-g))) * u;
                    H[(size_t)(rowb + rloc) * IDIM + col] = f2bf(hv);
                }
            }
        }
    }
}

// =====================================================================
// 8-phase 256x256 down GEMM, K=IDIM, coef folded in epilogue, bf16 Y.
// 8 waves (2M x 4N), per-wave 128x64.  LDS/buf: A[256][64]@0, B[256][64]@16384.
// =====================================================================
__global__ __launch_bounds__(512, 2) void gemm_down8(
    const unsigned short* __restrict__ H, const unsigned short* __restrict__ pool,
    unsigned short* __restrict__ Y,
    const float* __restrict__ wlb, const float* __restrict__ sgo,
    const int* __restrict__ cnt, const int* __restrict__ offs)
{
    int z = blockIdx.z;
    const unsigned short* B; const float* coef; int count, rowb;
    if (z == 0) {
        B = pool + (size_t)8 * DDIM * IDIM;
        coef = sgo; count = T_TOK; rowb = 0;
    } else {
        int e = z - 1;
        B = pool + (size_t)e * DDIM * IDIM;
        coef = wlb + (size_t)e * T_TOK;
        count = cnt[e]; rowb = T_TOK + offs[e];
    }
    int m0 = blockIdx.y * 256, n0 = blockIdx.x * 256;
    if (m0 >= count) return;
    int climit = (count + 127) & ~127;
    const int NT = IDIM / 64;   // 32

    __shared__ unsigned short lds[2][32768];   // 128 KiB

    int tid = threadIdx.x, wid = tid >> 6, l = tid & 63;
    int wm = wid >> 2, wn = wid & 3;           // wm 0..1, wn 0..3
    int lr = l & 15, lkg = l >> 4;

    int sb = tid & 7, sr = tid >> 3;
    int sk = (sb ^ (sr & 7)) << 3;
    const unsigned short* pah = H + (size_t)(rowb + m0 + sr) * IDIM + sk;
    const unsigned short* pb  = B + (size_t)(n0 + sr) * IDIM + sk;

#define DN_ST_A(sbuf, h, t) { \
    GLDS(pah + (size_t)((h) * 128) * IDIM + (t) * 64, (sbuf) + (h) * 8192 + tid * 8); \
    GLDS(pah + (size_t)((h) * 128 + 64) * IDIM + (t) * 64, (sbuf) + (h) * 8192 + 4096 + tid * 8); }
#define DN_ST_B(sbuf, h, t) { \
    GLDS(pb + (size_t)((h) * 128) * IDIM + (t) * 64, (sbuf) + 16384 + (h) * 8192 + tid * 8); \
    GLDS(pb + (size_t)((h) * 128 + 64) * IDIM + (t) * 64, (sbuf) + 16384 + (h) * 8192 + 4096 + tid * 8); }

    {
        unsigned short* s0 = &lds[0][0];
        DN_ST_A(s0, 0, 0); DN_ST_A(s0, 1, 0); DN_ST_B(s0, 0, 0); DN_ST_B(s0, 1, 0);
        unsigned short* s1 = &lds[1][0];
        DN_ST_A(s1, 0, 1); DN_ST_A(s1, 1, 1); DN_ST_B(s1, 0, 1); DN_ST_B(s1, 1, 1);
    }

    int xorc = (lr & 7) << 3;
    int kx0 = (lkg * 8) ^ xorc;
    int kx1 = (32 + lkg * 8) ^ xorc;
    int aoff[8], boff[4];
#pragma unroll
    for (int mf = 0; mf < 8; mf++)
        aoff[mf] = wm * 8192 + (mf * 16 + lr) * 64;
#pragma unroll
    for (int nf = 0; nf < 4; nf++)
        boff[nf] = 16384 + (wn * 64 + nf * 16 + lr) * 64;

    f32x4 zero = {0.f, 0.f, 0.f, 0.f};
    f32x4 acc[8][4];
#pragma unroll
    for (int m = 0; m < 8; m++)
#pragma unroll
        for (int n = 0; n < 4; n++) acc[m][n] = zero;

    bf16x8 a[4][2], b[4][2];

#pragma unroll 1
    for (int t = 0; t < NT; t++) {
        const unsigned short* cb = &lds[t & 1][0];
        unsigned short* sbuf = &lds[t & 1][0];
        bool stg = (t + 2 < NT);

        // ---- P1: mf0-3 x nf0-1 ----
        if (t == NT - 1) { asm volatile("s_waitcnt vmcnt(0)" ::: "memory"); }
        else             { asm volatile("s_waitcnt vmcnt(8)" ::: "memory"); }
        __builtin_amdgcn_s_barrier();
#pragma unroll
        for (int mf = 0; mf < 4; mf++) {
            a[mf][0] = *(const bf16x8*)(cb + aoff[mf] + kx0);
            a[mf][1] = *(const bf16x8*)(cb + aoff[mf] + kx1);
        }
#pragma unroll
        for (int nf = 0; nf < 2; nf++) {
            b[nf][0] = *(const bf16x8*)(cb + boff[nf] + kx0);
            b[nf][1] = *(const bf16x8*)(cb + boff[nf] + kx1);
        }
        __builtin_amdgcn_s_setprio(1);
#pragma unroll
        for (int kh = 0; kh < 2; kh++)
#pragma unroll
            for (int mf = 0; mf < 4; mf++)
#pragma unroll
                for (int nf = 0; nf < 2; nf++)
                    acc[mf][nf] = __builtin_amdgcn_mfma_f32_16x16x32_bf16(a[mf][kh], b[nf][kh], acc[mf][nf], 0, 0, 0);
        __builtin_amdgcn_s_setprio(0);

        // ---- P2: mf0-3 x nf2-3 ----
        __builtin_amdgcn_s_barrier();
#pragma unroll
        for (int nf = 2; nf < 4; nf++) {
            b[nf][0] = *(const bf16x8*)(cb + boff[nf] + kx0);
            b[nf][1] = *(const bf16x8*)(cb + boff[nf] + kx1);
        }
        __builtin_amdgcn_s_setprio(1);
#pragma unroll
        for (int kh = 0; kh < 2; kh++)
#pragma unroll
            for (int mf = 0; mf < 4; mf++)
#pragma unroll
                for (int nf = 2; nf < 4; nf++)
                    acc[mf][nf] = __builtin_amdgcn_mfma_f32_16x16x32_bf16(a[mf][kh], b[nf][kh], acc[mf][nf], 0, 0, 0);
        __builtin_amdgcn_s_setprio(0);

        // ---- P3: mf4-7 x nf0-1; stage B0(t+2) ----
        __builtin_amdgcn_s_barrier();
#pragma unroll
        for (int mf = 0; mf < 4; mf++) {
            a[mf][0] = *(const bf16x8*)(cb + aoff[4 + mf] + kx0);
            a[mf][1] = *(const bf16x8*)(cb + aoff[4 + mf] + kx1);
        }
        if (stg) { DN_ST_B(sbuf, 0, t + 2); }
        __builtin_amdgcn_s_setprio(1);
#pragma unroll
        for (int kh = 0; kh < 2; kh++)
#pragma unroll
            for (int mf = 0; mf < 4; mf++)
#pragma unroll
                for (int nf = 0; nf < 2; nf++)
                    acc[4 + mf][nf] = __builtin_amdgcn_mfma_f32_16x16x32_bf16(a[mf][kh], b[nf][kh], acc[4 + mf][nf], 0, 0, 0);
        __builtin_amdgcn_s_setprio(0);

        // ---- P4: mf4-7 x nf2-3; stage B1, A0, A1 (t+2) ----
        __builtin_amdgcn_s_barrier();
        if (stg) { DN_ST_B(sbuf, 1, t + 2); DN_ST_A(sbuf, 0, t + 2); DN_ST_A(sbuf, 1, t + 2); }
        __builtin_amdgcn_s_setprio(1);
#pragma unroll
        for (int kh = 0; kh < 2; kh++)
#pragma unroll
            for (int mf = 0; mf < 4; mf++)
#pragma unroll
                for (int nf = 2; nf < 4; nf++)
                    acc[4 + mf][nf] = __builtin_amdgcn_mfma_f32_16x16x32_bf16(a[mf][kh], b[nf][kh], acc[4 + mf][nf], 0, 0, 0);
        __builtin_amdgcn_s_setprio(0);
    }

    // ---- epilogue: coef * acc -> bf16 Y, guarded ----
#pragma unroll
    for (int mf = 0; mf < 8; mf++) {
        int rbase = m0 + wm * 128 + mf * 16 + lkg * 4;
        float cf[4];
#pragma unroll
        for (int r = 0; r < 4; r++) {
            int rloc = rbase + r;
            cf[r] = (rloc < climit) ? coef[rloc] : 0.f;
        }
#pragma unroll
        for (int nf = 0; nf < 4; nf++) {
            int col = n0 + wn * 64 + nf * 16 + lr;
#pragma unroll
            for (int r = 0; r < 4; r++) {
                int rloc = rbase + r;
                if (rloc < climit)
                    Y[(size_t)(rowb + rloc) * DDIM + col] = f2bf(cf[r] * acc[mf][nf][r]);
            }
        }
    }
}

// ---------------- Combine: out[t] = Y[t] + Y[r0] + Y[r1] (weights pre-applied) ----------------
__global__ __launch_bounds__(256) void combine_kernel(
    const unsigned short* __restrict__ Y, const int* __restrict__ te,
    const int* __restrict__ tp, const int* __restrict__ offs,
    float* __restrict__ out)
{
    int t = blockIdx.x * 2 + (threadIdx.x >> 7);
    int c = (threadIdx.x & 127) * 8;
    int e0 = te[2 * t], e1 = te[2 * t + 1];
    size_t r0 = (size_t)T_TOK + offs[e0] + tp[2 * t];
    size_t r1 = (size_t)T_TOK + offs[e1] + tp[2 * t + 1];

    us8 vs = *(const us8*)(Y + (size_t)t * DDIM + c);
    us8 v0 = *(const us8*)(Y + r0 * DDIM + c);
    us8 v1 = *(const us8*)(Y + r1 * DDIM + c);
    f4 o0, o1;
#pragma unroll
    for (int k = 0; k < 4; k++) {
        o0[k] = __uint_as_float((unsigned)vs[k] << 16)
              + __uint_as_float((unsigned)v0[k] << 16)
              + __uint_as_float((unsigned)v1[k] << 16);
        o1[k] = __uint_as_float((unsigned)vs[4 + k] << 16)
              + __uint_as_float((unsigned)v0[4 + k] << 16)
              + __uint_as_float((unsigned)v1[4 + k] << 16);
    }
    float* op = out + (size_t)t * DDIM + c;
    *(f4*)op = o0;
    *(f4*)(op + 4) = o1;
}

extern "C" void kernel_launch(void* const* d_in, const int* in_sizes, int n_in,
                              void* d_out, int out_size, void* d_ws, size_t ws_size,
                              hipStream_t stream)
{
    const float* x   = (const float*)d_in[0];
    const float* gw  = (const float*)d_in[1];
    const float* egw = (const float*)d_in[2];
    const float* euw = (const float*)d_in[3];
    const float* edw = (const float*)d_in[4];
    const float* sgp = (const float*)d_in[5];
    const float* sup = (const float*)d_in[6];
    const float* sdw = (const float*)d_in[7];
    const float* seg = (const float*)d_in[8];

    float* out0 = (float*)d_out;
    float* gate_out = out0 + (size_t)T_TOK * DDIM;

    // Workspace layout: byte-identical to the round-5 passing footprint.
    char* ws = (char*)d_ws;
    auto take = [&](size_t bytes) { char* p = ws; ws += (bytes + 255) & ~(size_t)255; return p; };
    unsigned short* xb   = (unsigned short*)take((size_t)T_TOK * DDIM * 2);
    float* wdense = (float*)take((size_t)T_TOK * NEXP * 4);
    float* sgo    = (float*)take((size_t)T_TOK * 4);
    int*   list   = (int*)take((size_t)NEXP * T_TOK * 4);
    float* wl     = (float*)take((size_t)NEXP * T_TOK * 4);
    int*   cnt    = (int*)take(256);
    int*   offs   = (int*)take(256);
    int*   te     = (int*)take((size_t)T_TOK * 2 * 4);
    int*   tp     = (int*)take((size_t)T_TOK * 2 * 4);
    unsigned short* pool = (unsigned short*)take((size_t)18 * NCH * DDIM * 2);
    unsigned short* H    = (unsigned short*)take((size_t)ROWS_TOT * IDIM * 2);
    unsigned short* Y    = (unsigned short*)take((size_t)ROWS_TOT * DDIM * 2);

    router_kernel<<<T_TOK / 4, 256, 0, stream>>>(x, gw, seg, gate_out, wdense, sgo);
    bucket_kernel<<<NEXP, 256, 0, stream>>>(wdense, list, wl, cnt, te, tp);
    scan_kernel<<<1, 64, 0, stream>>>(cnt, offs);
    cvt_kernel<<<(T_TOK * DDIM / 8) / 256, 256, 0, stream>>>(x, xb, T_TOK * DDIM / 8);

    // Gate+up in two N-chunks (weight pool reuse; H columns independent).
    for (int c = 0; c < 2; c++) {
        int c0 = c * NCH;
        wcvt_gu_kernel<<<dim3((NCH / 64) * 16, 18), 256, 0, stream>>>(
            egw, euw, sgp, sup, pool, c0);
        gemm_gateup8<<<dim3(NCH / 128, T_TOK / 256, 9), 512, 0, stream>>>(
            xb, pool, H, list, cnt, offs, c0);
    }

    // Down: single pass, K = IDIM, combine weights folded into the epilogue.
    wcvt_d_kernel<<<dim3((IDIM / 64) * 16, 9), 256, 0, stream>>>(edw, sdw, pool);
    gemm_down8<<<dim3(DDIM / 256, T_TOK / 256, 9), 512, 0, stream>>>(
        H, pool, Y, wl, sgo, cnt, offs);

    combine_kernel<<<T_TOK / 2, 256, 0, stream>>>(Y, te, tp, offs, out0);
}